// Round 1
// baseline (19744.250 us; speedup 1.0000x reference)
//
#include <hip/hip_runtime.h>

// ==== model dims (fixed by the reference) ====
constexpr int B_  = 2, S_ = 1024, T_ = 2048;   // T = B*S tokens
constexpr int D_  = 512, H_ = 8, DH_ = 64;
constexpr int L_  = 12, E_ = 8, FF_ = 2048;
constexpr int V_  = 32000, D3_ = 1536;

// ---------- helpers ----------
__device__ __forceinline__ float wred(float v){
#pragma unroll
  for (int off = 32; off; off >>= 1) v += __shfl_xor(v, off);
  return v;
}
__device__ __forceinline__ float gelu_f(float v){
  return 0.5f * v * (1.f + erff(v * 0.70710678118654752f));
}

// ---------- embedding: x[t,d] = tok[ids[t],d] + pos[t%S,d] ----------
__global__ void k_embed(const int* __restrict__ ids, const float* __restrict__ tok,
                        const float* __restrict__ pos, float* __restrict__ x){
  int t = blockIdx.x;
  int s = t & (S_ - 1);
  int id = ids[t];
  const float* tr = tok + (size_t)id * D_;
  const float* pr = pos + (size_t)s  * D_;
  float* xr = x + (size_t)t * D_;
  for (int d = threadIdx.x; d < D_; d += blockDim.x) xr[d] = tr[d] + pr[d];
}

// ---------- rmsnorm: h = x * rsqrt(mean(x^2)+eps) * w ----------
__global__ __launch_bounds__(256) void k_rmsnorm(const float* __restrict__ x,
                                                 const float* __restrict__ w,
                                                 float* __restrict__ h){
  int t = blockIdx.x;
  const float* xr = x + (size_t)t * D_;
  float* hr = h + (size_t)t * D_;
  float ss = 0.f;
  for (int d = threadIdx.x; d < D_; d += 256){ float v = xr[d]; ss += v * v; }
  ss = wred(ss);
  __shared__ float sp[4];
  __shared__ float sscale;
  if ((threadIdx.x & 63) == 0) sp[threadIdx.x >> 6] = ss;
  __syncthreads();
  if (threadIdx.x == 0){
    float tot = sp[0] + sp[1] + sp[2] + sp[3];
    sscale = rsqrtf(tot / (float)D_ + 1e-6f);
  }
  __syncthreads();
  float sc = sscale;
  for (int d = threadIdx.x; d < D_; d += 256) hr[d] = xr[d] * sc * w[d];
}

// ---------- generic fp32 GEMM: C[M,N] = A[M,K] @ B[K,N] (+bias) (+=) ----------
// 64x64 tile, BK=16, 256 threads, 4x4 per thread. M,N,K all multiples of 64/64/16.
template<bool HAS_BIAS, bool ACCUM>
__global__ __launch_bounds__(256) void k_gemm(const float* __restrict__ A,
                                              const float* __restrict__ Bm,
                                              const float* __restrict__ bias,
                                              float* __restrict__ C,
                                              int M, int N, int K){
  __shared__ float As[16][68];
  __shared__ float Bs[16][68];
  const int tid = threadIdx.x;
  const int row0 = blockIdx.y * 64, col0 = blockIdx.x * 64;
  const int ty = tid >> 4, tx = tid & 15;
  const int lam = tid >> 2, lak = (tid & 3) << 2;   // A loader: row lam, k-chunk lak
  const int lbk = tid >> 4, lbn = (tid & 15) << 2;  // B loader: k-row lbk, col lbn
  float acc[4][4] = {};
  const float* Arow = A + (size_t)(row0 + lam) * K;
  for (int k0 = 0; k0 < K; k0 += 16){
    float4 av = *reinterpret_cast<const float4*>(Arow + k0 + lak);
    As[lak + 0][lam] = av.x; As[lak + 1][lam] = av.y;
    As[lak + 2][lam] = av.z; As[lak + 3][lam] = av.w;
    *reinterpret_cast<float4*>(&Bs[lbk][lbn]) =
        *reinterpret_cast<const float4*>(Bm + (size_t)(k0 + lbk) * N + col0 + lbn);
    __syncthreads();
#pragma unroll
    for (int kk = 0; kk < 16; kk++){
      const float4 a = *reinterpret_cast<const float4*>(&As[kk][ty << 2]);
      const float4 b = *reinterpret_cast<const float4*>(&Bs[kk][tx << 2]);
      const float ar[4] = {a.x, a.y, a.z, a.w};
      const float br[4] = {b.x, b.y, b.z, b.w};
#pragma unroll
      for (int i = 0; i < 4; i++)
#pragma unroll
        for (int j = 0; j < 4; j++) acc[i][j] = fmaf(ar[i], br[j], acc[i][j]);
    }
    __syncthreads();
  }
  const int c0 = col0 + (tx << 2);
  float4 bv = make_float4(0.f, 0.f, 0.f, 0.f);
  if (HAS_BIAS) bv = *reinterpret_cast<const float4*>(bias + c0);
#pragma unroll
  for (int i = 0; i < 4; i++){
    size_t r = (size_t)(row0 + (ty << 2) + i);
    float* Cp = C + r * (size_t)N + c0;
    float v0 = acc[i][0] + bv.x, v1 = acc[i][1] + bv.y;
    float v2 = acc[i][2] + bv.z, v3 = acc[i][3] + bv.w;
    if (ACCUM){
      float4 cv = *reinterpret_cast<const float4*>(Cp);
      cv.x += v0; cv.y += v1; cv.z += v2; cv.w += v3;
      *reinterpret_cast<float4*>(Cp) = cv;
    } else {
      *reinterpret_cast<float4*>(Cp) = make_float4(v0, v1, v2, v3);
    }
  }
}

// ---------- causal attention: one wave per (b,h,q) row, online softmax ----------
__global__ __launch_bounds__(256) void k_attn(const float* __restrict__ qkv,
                                              float* __restrict__ o){
  int wid  = blockIdx.x * 4 + (threadIdx.x >> 6);   // 0 .. B*H*S-1
  int lane = threadIdx.x & 63;
  int q = wid & (S_ - 1);
  int h = (wid >> 10) & (H_ - 1);
  int b = wid >> 13;
  int t = (b << 10) + q;
  // scale folded into q (exact: *0.125 is a power of two)
  float qv = qkv[(size_t)t * D3_ + h * DH_ + lane] * 0.125f;
  const float* kbase = qkv + (size_t)(b << 10) * D3_ + D_ + h * DH_;
  float m = -1e30f, l = 0.f, acc = 0.f;
  for (int k = 0; k <= q; k++){
    const float* kb = kbase + (size_t)k * D3_;
    float s = qv * kb[lane];
    s = wred(s);
    float vv = kb[512 + lane];           // V section lives +512 after K
    float mn = fmaxf(m, s);
    float cr = __expf(m - mn);
    float w  = __expf(s - mn);
    l   = l * cr + w;
    acc = acc * cr + w * vv;
    m = mn;
  }
  o[(size_t)t * D_ + h * DH_ + lane] = acc / l;
}

// ---------- router: logits, softmax, top-1, per-expert stats ----------
__global__ __launch_bounds__(64) void k_router(const float* __restrict__ h2,
                                               const float* __restrict__ rW,  // [D,E] (layer slice)
                                               const float* __restrict__ rb,  // [E]
                                               float* __restrict__ rl_out,    // [T,E]
                                               float* __restrict__ topw, int* __restrict__ topi,
                                               int* __restrict__ counts, float* __restrict__ psum){
  int t = blockIdx.x, lane = threadIdx.x;
  const float* hr = h2 + (size_t)t * D_;
  float acc[8] = {0,0,0,0,0,0,0,0};
  for (int d = lane; d < D_; d += 64){
    float hv = hr[d];
    const float* wr = rW + (size_t)d * E_;
    float4 w0 = *reinterpret_cast<const float4*>(wr);
    float4 w1 = *reinterpret_cast<const float4*>(wr + 4);
    acc[0] += hv * w0.x; acc[1] += hv * w0.y; acc[2] += hv * w0.z; acc[3] += hv * w0.w;
    acc[4] += hv * w1.x; acc[5] += hv * w1.y; acc[6] += hv * w1.z; acc[7] += hv * w1.w;
  }
  float rl[8];
#pragma unroll
  for (int e = 0; e < 8; e++) rl[e] = wred(acc[e]) + rb[e];
  float mx = rl[0];
#pragma unroll
  for (int e = 1; e < 8; e++) mx = fmaxf(mx, rl[e]);
  float p[8], s = 0.f;
#pragma unroll
  for (int e = 0; e < 8; e++){ p[e] = __expf(rl[e] - mx); s += p[e]; }
  float inv = 1.f / s;
  int arg = 0; float best = rl[0];
#pragma unroll
  for (int e = 1; e < 8; e++) if (rl[e] > best){ best = rl[e]; arg = e; }
  if (lane == 0){
#pragma unroll
    for (int e = 0; e < 8; e++) rl_out[(size_t)t * E_ + e] = rl[e];
    topw[t] = p[arg] * inv;
    topi[t] = arg;
    atomicAdd(&counts[arg], 1);
#pragma unroll
    for (int e = 0; e < 8; e++) atomicAdd(&psum[e], p[e] * inv);
  }
}

// ---------- routing finalize: prefix sums + aux accumulation ----------
__global__ void k_route_fin(const int* __restrict__ counts, const float* __restrict__ psum,
                            int* __restrict__ seg, int* __restrict__ cursor,
                            float* __restrict__ aux){
  if (threadIdx.x == 0){
    int s = 0; float av = 0.f;
#pragma unroll
    for (int e = 0; e < 8; e++){
      seg[e] = s; cursor[e] = s; s += counts[e];
      av += ((float)counts[e] / (float)T_) * (psum[e] / (float)T_);
    }
    seg[8] = s;
    aux[0] += 8.f * av;
  }
}

// ---------- scatter tokens into expert-grouped order ----------
__global__ void k_scatter(const int* __restrict__ topi, int* __restrict__ cursor,
                          int* __restrict__ perm){
  int t = blockIdx.x * blockDim.x + threadIdx.x;
  if (t < T_){
    int e = topi[t];
    int p = atomicAdd(&cursor[e], 1);
    perm[p] = t;
  }
}

// ---------- MoE FFN-1: hid[g,:] = gelu(h2[perm[g],:] @ W1[e] + b1[e]) ----------
__global__ __launch_bounds__(256) void k_moe_ff1(const float* __restrict__ h2,
                                                 const float* __restrict__ W1,  // [E,D,FF] slice
                                                 const float* __restrict__ b1,  // [E,FF] slice
                                                 float* __restrict__ hid,
                                                 const int* __restrict__ perm,
                                                 const int* __restrict__ seg){
  int e = blockIdx.z;
  int s0 = seg[e], cnt = seg[e + 1] - s0;
  int row0 = blockIdx.y * 64;
  if (row0 >= cnt) return;
  const float* Bp = W1 + (size_t)e * D_ * FF_;
  const float* bp = b1 + (size_t)e * FF_;
  __shared__ float As[16][68];
  __shared__ float Bs[16][68];
  const int tid = threadIdx.x;
  const int ty = tid >> 4, tx = tid & 15;
  const int lam = tid >> 2, lak = (tid & 3) << 2;
  const int lbk = tid >> 4, lbn = (tid & 15) << 2;
  const int col0 = blockIdx.x * 64;
  float acc[4][4] = {};
  int ra = row0 + lam;
  const float* Arow = (ra < cnt) ? (h2 + (size_t)perm[s0 + ra] * D_) : nullptr;
  for (int k0 = 0; k0 < D_; k0 += 16){
    float4 av = make_float4(0.f, 0.f, 0.f, 0.f);
    if (Arow) av = *reinterpret_cast<const float4*>(Arow + k0 + lak);
    As[lak + 0][lam] = av.x; As[lak + 1][lam] = av.y;
    As[lak + 2][lam] = av.z; As[lak + 3][lam] = av.w;
    *reinterpret_cast<float4*>(&Bs[lbk][lbn]) =
        *reinterpret_cast<const float4*>(Bp + (size_t)(k0 + lbk) * FF_ + col0 + lbn);
    __syncthreads();
#pragma unroll
    for (int kk = 0; kk < 16; kk++){
      const float4 a = *reinterpret_cast<const float4*>(&As[kk][ty << 2]);
      const float4 b = *reinterpret_cast<const float4*>(&Bs[kk][tx << 2]);
      const float ar[4] = {a.x, a.y, a.z, a.w};
      const float br[4] = {b.x, b.y, b.z, b.w};
#pragma unroll
      for (int i = 0; i < 4; i++)
#pragma unroll
        for (int j = 0; j < 4; j++) acc[i][j] = fmaf(ar[i], br[j], acc[i][j]);
    }
    __syncthreads();
  }
  const int c0 = col0 + (tx << 2);
  float4 bv = *reinterpret_cast<const float4*>(bp + c0);
#pragma unroll
  for (int i = 0; i < 4; i++){
    int r = row0 + (ty << 2) + i;
    if (r < cnt){
      float4 ov;
      ov.x = gelu_f(acc[i][0] + bv.x); ov.y = gelu_f(acc[i][1] + bv.y);
      ov.z = gelu_f(acc[i][2] + bv.z); ov.w = gelu_f(acc[i][3] + bv.w);
      *reinterpret_cast<float4*>(&hid[(size_t)(s0 + r) * FF_ + c0]) = ov;
    }
  }
}

// ---------- MoE FFN-2: x[perm[g],:] += topw * (hid[g,:] @ W2[e] + b2[e]) ----------
__global__ __launch_bounds__(256) void k_moe_ff2(const float* __restrict__ hid,
                                                 const float* __restrict__ W2,  // [E,FF,D] slice
                                                 const float* __restrict__ b2,  // [E,D] slice
                                                 float* __restrict__ x,
                                                 const int* __restrict__ perm,
                                                 const int* __restrict__ seg,
                                                 const float* __restrict__ topw){
  int e = blockIdx.z;
  int s0 = seg[e], cnt = seg[e + 1] - s0;
  int row0 = blockIdx.y * 64;
  if (row0 >= cnt) return;
  const float* Bp = W2 + (size_t)e * FF_ * D_;
  const float* bp = b2 + (size_t)e * D_;
  __shared__ float As[16][68];
  __shared__ float Bs[16][68];
  const int tid = threadIdx.x;
  const int ty = tid >> 4, tx = tid & 15;
  const int lam = tid >> 2, lak = (tid & 3) << 2;
  const int lbk = tid >> 4, lbn = (tid & 15) << 2;
  const int col0 = blockIdx.x * 64;
  float acc[4][4] = {};
  int ra = row0 + lam;
  const float* Arow = (ra < cnt) ? (hid + (size_t)(s0 + ra) * FF_) : nullptr;
  for (int k0 = 0; k0 < FF_; k0 += 16){
    float4 av = make_float4(0.f, 0.f, 0.f, 0.f);
    if (Arow) av = *reinterpret_cast<const float4*>(Arow + k0 + lak);
    As[lak + 0][lam] = av.x; As[lak + 1][lam] = av.y;
    As[lak + 2][lam] = av.z; As[lak + 3][lam] = av.w;
    *reinterpret_cast<float4*>(&Bs[lbk][lbn]) =
        *reinterpret_cast<const float4*>(Bp + (size_t)(k0 + lbk) * D_ + col0 + lbn);
    __syncthreads();
#pragma unroll
    for (int kk = 0; kk < 16; kk++){
      const float4 a = *reinterpret_cast<const float4*>(&As[kk][ty << 2]);
      const float4 b = *reinterpret_cast<const float4*>(&Bs[kk][tx << 2]);
      const float ar[4] = {a.x, a.y, a.z, a.w};
      const float br[4] = {b.x, b.y, b.z, b.w};
#pragma unroll
      for (int i = 0; i < 4; i++)
#pragma unroll
        for (int j = 0; j < 4; j++) acc[i][j] = fmaf(ar[i], br[j], acc[i][j]);
    }
    __syncthreads();
  }
  const int c0 = col0 + (tx << 2);
  float4 bv = *reinterpret_cast<const float4*>(bp + c0);
#pragma unroll
  for (int i = 0; i < 4; i++){
    int r = row0 + (ty << 2) + i;
    if (r < cnt){
      int t = perm[s0 + r];
      float w = topw[t];
      float* xr = x + (size_t)t * D_ + c0;
      float4 xv = *reinterpret_cast<const float4*>(xr);
      xv.x += w * (acc[i][0] + bv.x); xv.y += w * (acc[i][1] + bv.y);
      xv.z += w * (acc[i][2] + bv.z); xv.w += w * (acc[i][3] + bv.w);
      *reinterpret_cast<float4*>(xr) = xv;
    }
  }
}

// ======================= host launcher =======================
extern "C" void kernel_launch(void* const* d_in, const int* in_sizes, int n_in,
                              void* d_out, int out_size, void* d_ws, size_t ws_size,
                              hipStream_t stream){
  const int*   ids  = (const int*)  d_in[0];
  const float* tok  = (const float*)d_in[1];
  const float* pos  = (const float*)d_in[2];
  const float* Wqkv = (const float*)d_in[3];
  const float* bqkv = (const float*)d_in[4];
  const float* Wo   = (const float*)d_in[5];
  const float* bo   = (const float*)d_in[6];
  const float* rW   = (const float*)d_in[7];
  const float* rb   = (const float*)d_in[8];
  const float* eW1  = (const float*)d_in[9];
  const float* eb1  = (const float*)d_in[10];
  const float* eW2  = (const float*)d_in[11];
  const float* eb2  = (const float*)d_in[12];
  const float* n1w  = (const float*)d_in[13];
  const float* n2w  = (const float*)d_in[14];
  const float* noww = (const float*)d_in[15];
  const float* lmW  = (const float*)d_in[16];

  float* out    = (float*)d_out;
  float* logits = out;                             // [T,V]
  float* aux    = out + (size_t)T_ * V_;           // [1]
  float* rlog   = aux + 1;                         // [L,T,E]

  // workspace layout (~42 MB total)
  float* ws = (float*)d_ws;
  size_t off = 0;
  float* x     = ws + off; off += (size_t)T_ * D_;
  float* h     = ws + off; off += (size_t)T_ * D_;
  float* qkv   = ws + off; off += (size_t)T_ * D3_;
  float* attno = ws + off; off += (size_t)T_ * D_;
  float* hid   = ws + off; off += (size_t)T_ * FF_;
  float* topw  = ws + off; off += T_;
  float* psum  = ws + off; off += E_;              // psum[8] then counts[8] (contiguous memset)
  int* counts  = (int*)(ws + off); off += E_;
  int* topi    = (int*)(ws + off); off += T_;
  int* perm    = (int*)(ws + off); off += T_;
  int* seg     = (int*)(ws + off); off += (E_ + 1);
  int* cursor  = (int*)(ws + off); off += E_;

  hipMemsetAsync(aux, 0, sizeof(float), stream);
  k_embed<<<T_, 256, 0, stream>>>(ids, tok, pos, x);

  for (int l = 0; l < L_; l++){
    // --- attention block ---
    k_rmsnorm<<<T_, 256, 0, stream>>>(x, n1w + (size_t)l * D_, h);
    k_gemm<true, false><<<dim3(D3_ / 64, T_ / 64), 256, 0, stream>>>(
        h, Wqkv + (size_t)l * D_ * D3_, bqkv + (size_t)l * D3_, qkv, T_, D3_, D_);
    k_attn<<<(B_ * H_ * S_) / 4, 256, 0, stream>>>(qkv, attno);
    k_gemm<true, true><<<dim3(D_ / 64, T_ / 64), 256, 0, stream>>>(
        attno, Wo + (size_t)l * D_ * D_, bo + (size_t)l * D_, x, T_, D_, D_);
    // --- MoE block ---
    k_rmsnorm<<<T_, 256, 0, stream>>>(x, n2w + (size_t)l * D_, h);
    hipMemsetAsync(psum, 0, 2 * E_ * sizeof(float), stream);   // psum + counts
    k_router<<<T_, 64, 0, stream>>>(h, rW + (size_t)l * D_ * E_, rb + (size_t)l * E_,
                                    rlog + (size_t)l * T_ * E_, topw, topi, counts, psum);
    k_route_fin<<<1, 64, 0, stream>>>(counts, psum, seg, cursor, aux);
    k_scatter<<<T_ / 256, 256, 0, stream>>>(topi, cursor, perm);
    k_moe_ff1<<<dim3(FF_ / 64, T_ / 64, E_), 256, 0, stream>>>(
        h, eW1 + (size_t)l * E_ * D_ * FF_, eb1 + (size_t)l * E_ * FF_, hid, perm, seg);
    k_moe_ff2<<<dim3(D_ / 64, T_ / 64, E_), 256, 0, stream>>>(
        hid, eW2 + (size_t)l * E_ * FF_ * D_, eb2 + (size_t)l * E_ * D_, x, perm, seg, topw);
  }

  // --- final norm + LM head ---
  k_rmsnorm<<<T_, 256, 0, stream>>>(x, noww, h);
  k_gemm<false, false><<<dim3(V_ / 64, T_ / 64), 256, 0, stream>>>(
      h, lmW, nullptr, logits, T_, V_, D_);
}

// Round 2
// 13113.506 us; speedup vs baseline: 1.5056x; 1.5056x over previous
//
#include <hip/hip_runtime.h>

// ==== model dims (fixed by the reference) ====
constexpr int B_  = 2, S_ = 1024, T_ = 2048;   // T = B*S tokens
constexpr int D_  = 512, H_ = 8, DH_ = 64;
constexpr int L_  = 12, E_ = 8, FF_ = 2048;
constexpr int V_  = 32000, D3_ = 1536;

// ---------- helpers ----------
__device__ __forceinline__ float wred(float v){
#pragma unroll
  for (int off = 32; off; off >>= 1) v += __shfl_xor(v, off);
  return v;
}
__device__ __forceinline__ float wredmax(float v){
#pragma unroll
  for (int off = 32; off; off >>= 1) v = fmaxf(v, __shfl_xor(v, off));
  return v;
}
__device__ __forceinline__ float gelu_f(float v){
  return 0.5f * v * (1.f + erff(v * 0.70710678118654752f));
}

// ---------- embedding: x[t,d] = tok[ids[t],d] + pos[t%S,d] ----------
__global__ void k_embed(const int* __restrict__ ids, const float* __restrict__ tok,
                        const float* __restrict__ pos, float* __restrict__ x){
  int t = blockIdx.x;
  int s = t & (S_ - 1);
  int id = ids[t];
  const float* tr = tok + (size_t)id * D_;
  const float* pr = pos + (size_t)s  * D_;
  float* xr = x + (size_t)t * D_;
  for (int d = threadIdx.x; d < D_; d += blockDim.x) xr[d] = tr[d] + pr[d];
}

// ---------- rmsnorm: h = x * rsqrt(mean(x^2)+eps) * w ----------
__global__ __launch_bounds__(256) void k_rmsnorm(const float* __restrict__ x,
                                                 const float* __restrict__ w,
                                                 float* __restrict__ h){
  int t = blockIdx.x;
  const float* xr = x + (size_t)t * D_;
  float* hr = h + (size_t)t * D_;
  float ss = 0.f;
  for (int d = threadIdx.x; d < D_; d += 256){ float v = xr[d]; ss += v * v; }
  ss = wred(ss);
  __shared__ float sp[4];
  __shared__ float sscale;
  if ((threadIdx.x & 63) == 0) sp[threadIdx.x >> 6] = ss;
  __syncthreads();
  if (threadIdx.x == 0){
    float tot = sp[0] + sp[1] + sp[2] + sp[3];
    sscale = rsqrtf(tot / (float)D_ + 1e-6f);
  }
  __syncthreads();
  float sc = sscale;
  for (int d = threadIdx.x; d < D_; d += 256) hr[d] = xr[d] * sc * w[d];
}

// ---------- generic fp32 GEMM: C[M,N] = A[M,K] @ B[K,N] (+bias) (+=) ----------
template<bool HAS_BIAS, bool ACCUM>
__global__ __launch_bounds__(256) void k_gemm(const float* __restrict__ A,
                                              const float* __restrict__ Bm,
                                              const float* __restrict__ bias,
                                              float* __restrict__ C,
                                              int M, int N, int K){
  __shared__ float As[16][68];
  __shared__ float Bs[16][68];
  const int tid = threadIdx.x;
  const int row0 = blockIdx.y * 64, col0 = blockIdx.x * 64;
  const int ty = tid >> 4, tx = tid & 15;
  const int lam = tid >> 2, lak = (tid & 3) << 2;   // A loader: row lam, k-chunk lak
  const int lbk = tid >> 4, lbn = (tid & 15) << 2;  // B loader: k-row lbk, col lbn
  float acc[4][4] = {};
  const float* Arow = A + (size_t)(row0 + lam) * K;
  for (int k0 = 0; k0 < K; k0 += 16){
    float4 av = *reinterpret_cast<const float4*>(Arow + k0 + lak);
    As[lak + 0][lam] = av.x; As[lak + 1][lam] = av.y;
    As[lak + 2][lam] = av.z; As[lak + 3][lam] = av.w;
    *reinterpret_cast<float4*>(&Bs[lbk][lbn]) =
        *reinterpret_cast<const float4*>(Bm + (size_t)(k0 + lbk) * N + col0 + lbn);
    __syncthreads();
#pragma unroll
    for (int kk = 0; kk < 16; kk++){
      const float4 a = *reinterpret_cast<const float4*>(&As[kk][ty << 2]);
      const float4 b = *reinterpret_cast<const float4*>(&Bs[kk][tx << 2]);
      const float ar[4] = {a.x, a.y, a.z, a.w};
      const float br[4] = {b.x, b.y, b.z, b.w};
#pragma unroll
      for (int i = 0; i < 4; i++)
#pragma unroll
        for (int j = 0; j < 4; j++) acc[i][j] = fmaf(ar[i], br[j], acc[i][j]);
    }
    __syncthreads();
  }
  const int c0 = col0 + (tx << 2);
  float4 bv = make_float4(0.f, 0.f, 0.f, 0.f);
  if (HAS_BIAS) bv = *reinterpret_cast<const float4*>(bias + c0);
#pragma unroll
  for (int i = 0; i < 4; i++){
    size_t r = (size_t)(row0 + (ty << 2) + i);
    float* Cp = C + r * (size_t)N + c0;
    float v0 = acc[i][0] + bv.x, v1 = acc[i][1] + bv.y;
    float v2 = acc[i][2] + bv.z, v3 = acc[i][3] + bv.w;
    if (ACCUM){
      float4 cv = *reinterpret_cast<const float4*>(Cp);
      cv.x += v0; cv.y += v1; cv.z += v2; cv.w += v3;
      *reinterpret_cast<float4*>(Cp) = cv;
    } else {
      *reinterpret_cast<float4*>(Cp) = make_float4(v0, v1, v2, v3);
    }
  }
}

// ---------- causal attention v2: tiled flash-style, fp32 VALU ----------
// Block = 256 thr / 4 waves, one (b,h), 8 query rows (2 per wave).
// K tile: row-major, XOR chunk-swizzled (chunk ^= row&7) -> conflict-free b128.
// V tile: transposed + same swizzle -> conflict-free b128 along key axis.
// Scores: lane = key, q broadcast via readlane. PV: lane = dim, p broadcast.
__global__ __launch_bounds__(256) void k_attn2(const float* __restrict__ qkv,
                                               float* __restrict__ o){
  __shared__ float Ks[64 * 64];
  __shared__ float Vt[64 * 64];
  __shared__ float ps[4][2][64];
  const int tid = threadIdx.x;
  const int w = tid >> 6, lane = tid & 63;
  const int bid = blockIdx.x;
  const int qb = bid & 127;          // S/8 = 128 q-blocks
  const int h  = (bid >> 7) & 7;
  const int b  = bid >> 10;
  const int qbase = qb << 3;
  const int qr0 = qbase + (w << 1), qr1 = qr0 + 1;
  const size_t bbase = (size_t)(b << 10) * D3_;
  const int hoff = h * 64;
  // q rows into registers (lane = d), 1/sqrt(64) folded (exact pow2)
  float q0v = qkv[bbase + (size_t)qr0 * D3_ + hoff + lane] * 0.125f;
  float q1v = qkv[bbase + (size_t)qr1 * D3_ + hoff + lane] * 0.125f;
  float m0 = -1e30f, l0 = 0.f, a0 = 0.f;
  float m1 = -1e30f, l1 = 0.f, a1 = 0.f;
  const int nt = ((qbase + 7) >> 6) + 1;
  const int jr = tid >> 2, cg = tid & 3;           // staging: row, chunk-group
  for (int jt = 0; jt < nt; jt++){
    const int j0 = jt << 6;
    __syncthreads();
    // ---- stage K (swizzled row-major) and V (swizzled transposed) ----
    const float* krow = qkv + bbase + (size_t)(j0 + jr) * D3_ + 512 + hoff;
#pragma unroll
    for (int cc = 0; cc < 4; cc++){
      const int c = cg + (cc << 2);
      const float4 kv4 = *reinterpret_cast<const float4*>(krow + (c << 2));
      *reinterpret_cast<float4*>(&Ks[(jr << 6) + ((c ^ (jr & 7)) << 2)]) = kv4;
      const float4 vv4 = *reinterpret_cast<const float4*>(krow + 512 + (c << 2));
      const int d0 = c << 2, jh = jr >> 2, jl = jr & 3;
      Vt[((d0 + 0) << 6) + ((jh ^ ((d0 + 0) & 7)) << 2) + jl] = vv4.x;
      Vt[((d0 + 1) << 6) + ((jh ^ ((d0 + 1) & 7)) << 2) + jl] = vv4.y;
      Vt[((d0 + 2) << 6) + ((jh ^ ((d0 + 2) & 7)) << 2) + jl] = vv4.z;
      Vt[((d0 + 3) << 6) + ((jh ^ ((d0 + 3) & 7)) << 2) + jl] = vv4.w;
    }
    __syncthreads();
    // ---- scores: lane = key index j ----
    float s0 = 0.f, s1 = 0.f;
#pragma unroll
    for (int c = 0; c < 16; c++){
      const float4 kx = *reinterpret_cast<const float4*>(
          &Ks[(lane << 6) + ((c ^ (lane & 7)) << 2)]);
      const float kr[4] = {kx.x, kx.y, kx.z, kx.w};
#pragma unroll
      for (int u = 0; u < 4; u++){
        const int d = (c << 2) + u;
        s0 = fmaf(__shfl(q0v, d), kr[u], s0);
        s1 = fmaf(__shfl(q1v, d), kr[u], s1);
      }
    }
    // ---- online softmax (per query) ----
    const int jg = j0 + lane;
    const float s0m = (jg <= qr0) ? s0 : -1e30f;
    const float s1m = (jg <= qr1) ? s1 : -1e30f;
    const float mn0 = fmaxf(m0, wredmax(s0m));
    const float mn1 = fmaxf(m1, wredmax(s1m));
    const float p0 = __expf(s0m - mn0);
    const float p1 = __expf(s1m - mn1);
    const float cr0 = __expf(m0 - mn0);
    const float cr1 = __expf(m1 - mn1);
    l0 = l0 * cr0 + wred(p0);
    l1 = l1 * cr1 + wred(p1);
    a0 *= cr0; a1 *= cr1;
    m0 = mn0; m1 = mn1;
    ps[w][0][lane] = p0;
    ps[w][1][lane] = p1;
    // ---- PV: lane = output dim d ----
#pragma unroll
    for (int c = 0; c < 16; c++){
      const float4 vx = *reinterpret_cast<const float4*>(
          &Vt[(lane << 6) + ((c ^ (lane & 7)) << 2)]);
      const float4 p0v = *reinterpret_cast<const float4*>(&ps[w][0][c << 2]);
      const float4 p1v = *reinterpret_cast<const float4*>(&ps[w][1][c << 2]);
      a0 = fmaf(p0v.x, vx.x, a0); a0 = fmaf(p0v.y, vx.y, a0);
      a0 = fmaf(p0v.z, vx.z, a0); a0 = fmaf(p0v.w, vx.w, a0);
      a1 = fmaf(p1v.x, vx.x, a1); a1 = fmaf(p1v.y, vx.y, a1);
      a1 = fmaf(p1v.z, vx.z, a1); a1 = fmaf(p1v.w, vx.w, a1);
    }
  }
  const int t0 = (b << 10) + qr0;
  o[(size_t)t0 * D_ + hoff + lane]       = a0 / l0;
  o[(size_t)(t0 + 1) * D_ + hoff + lane] = a1 / l1;
}

// ---------- router: logits, softmax, top-1, per-expert stats ----------
__global__ __launch_bounds__(64) void k_router(const float* __restrict__ h2,
                                               const float* __restrict__ rW,
                                               const float* __restrict__ rb,
                                               float* __restrict__ rl_out,
                                               float* __restrict__ topw, int* __restrict__ topi,
                                               int* __restrict__ counts, float* __restrict__ psum){
  int t = blockIdx.x, lane = threadIdx.x;
  const float* hr = h2 + (size_t)t * D_;
  float acc[8] = {0,0,0,0,0,0,0,0};
  for (int d = lane; d < D_; d += 64){
    float hv = hr[d];
    const float* wr = rW + (size_t)d * E_;
    float4 w0 = *reinterpret_cast<const float4*>(wr);
    float4 w1 = *reinterpret_cast<const float4*>(wr + 4);
    acc[0] += hv * w0.x; acc[1] += hv * w0.y; acc[2] += hv * w0.z; acc[3] += hv * w0.w;
    acc[4] += hv * w1.x; acc[5] += hv * w1.y; acc[6] += hv * w1.z; acc[7] += hv * w1.w;
  }
  float rl[8];
#pragma unroll
  for (int e = 0; e < 8; e++) rl[e] = wred(acc[e]) + rb[e];
  float mx = rl[0];
#pragma unroll
  for (int e = 1; e < 8; e++) mx = fmaxf(mx, rl[e]);
  float p[8], s = 0.f;
#pragma unroll
  for (int e = 0; e < 8; e++){ p[e] = __expf(rl[e] - mx); s += p[e]; }
  float inv = 1.f / s;
  int arg = 0; float best = rl[0];
#pragma unroll
  for (int e = 1; e < 8; e++) if (rl[e] > best){ best = rl[e]; arg = e; }
  if (lane == 0){
#pragma unroll
    for (int e = 0; e < 8; e++) rl_out[(size_t)t * E_ + e] = rl[e];
    topw[t] = p[arg] * inv;
    topi[t] = arg;
    atomicAdd(&counts[arg], 1);
#pragma unroll
    for (int e = 0; e < 8; e++) atomicAdd(&psum[e], p[e] * inv);
  }
}

// ---------- routing finalize: prefix sums + aux accumulation ----------
__global__ void k_route_fin(const int* __restrict__ counts, const float* __restrict__ psum,
                            int* __restrict__ seg, int* __restrict__ cursor,
                            float* __restrict__ aux){
  if (threadIdx.x == 0){
    int s = 0; float av = 0.f;
#pragma unroll
    for (int e = 0; e < 8; e++){
      seg[e] = s; cursor[e] = s; s += counts[e];
      av += ((float)counts[e] / (float)T_) * (psum[e] / (float)T_);
    }
    seg[8] = s;
    aux[0] += 8.f * av;
  }
}

// ---------- scatter tokens into expert-grouped order ----------
__global__ void k_scatter(const int* __restrict__ topi, int* __restrict__ cursor,
                          int* __restrict__ perm){
  int t = blockIdx.x * blockDim.x + threadIdx.x;
  if (t < T_){
    int e = topi[t];
    int p = atomicAdd(&cursor[e], 1);
    perm[p] = t;
  }
}

// ---------- MoE FFN-1: hid[g,:] = gelu(h2[perm[g],:] @ W1[e] + b1[e]) ----------
__global__ __launch_bounds__(256) void k_moe_ff1(const float* __restrict__ h2,
                                                 const float* __restrict__ W1,
                                                 const float* __restrict__ b1,
                                                 float* __restrict__ hid,
                                                 const int* __restrict__ perm,
                                                 const int* __restrict__ seg){
  int e = blockIdx.z;
  int s0 = seg[e], cnt = seg[e + 1] - s0;
  int row0 = blockIdx.y * 64;
  if (row0 >= cnt) return;
  const float* Bp = W1 + (size_t)e * D_ * FF_;
  const float* bp = b1 + (size_t)e * FF_;
  __shared__ float As[16][68];
  __shared__ float Bs[16][68];
  const int tid = threadIdx.x;
  const int ty = tid >> 4, tx = tid & 15;
  const int lam = tid >> 2, lak = (tid & 3) << 2;
  const int lbk = tid >> 4, lbn = (tid & 15) << 2;
  const int col0 = blockIdx.x * 64;
  float acc[4][4] = {};
  int ra = row0 + lam;
  const float* Arow = (ra < cnt) ? (h2 + (size_t)perm[s0 + ra] * D_) : nullptr;
  for (int k0 = 0; k0 < D_; k0 += 16){
    float4 av = make_float4(0.f, 0.f, 0.f, 0.f);
    if (Arow) av = *reinterpret_cast<const float4*>(Arow + k0 + lak);
    As[lak + 0][lam] = av.x; As[lak + 1][lam] = av.y;
    As[lak + 2][lam] = av.z; As[lak + 3][lam] = av.w;
    *reinterpret_cast<float4*>(&Bs[lbk][lbn]) =
        *reinterpret_cast<const float4*>(Bp + (size_t)(k0 + lbk) * FF_ + col0 + lbn);
    __syncthreads();
#pragma unroll
    for (int kk = 0; kk < 16; kk++){
      const float4 a = *reinterpret_cast<const float4*>(&As[kk][ty << 2]);
      const float4 b = *reinterpret_cast<const float4*>(&Bs[kk][tx << 2]);
      const float ar[4] = {a.x, a.y, a.z, a.w};
      const float br[4] = {b.x, b.y, b.z, b.w};
#pragma unroll
      for (int i = 0; i < 4; i++)
#pragma unroll
        for (int j = 0; j < 4; j++) acc[i][j] = fmaf(ar[i], br[j], acc[i][j]);
    }
    __syncthreads();
  }
  const int c0 = col0 + (tx << 2);
  float4 bv = *reinterpret_cast<const float4*>(bp + c0);
#pragma unroll
  for (int i = 0; i < 4; i++){
    int r = row0 + (ty << 2) + i;
    if (r < cnt){
      float4 ov;
      ov.x = gelu_f(acc[i][0] + bv.x); ov.y = gelu_f(acc[i][1] + bv.y);
      ov.z = gelu_f(acc[i][2] + bv.z); ov.w = gelu_f(acc[i][3] + bv.w);
      *reinterpret_cast<float4*>(&hid[(size_t)(s0 + r) * FF_ + c0]) = ov;
    }
  }
}

// ---------- MoE FFN-2: x[perm[g],:] += topw * (hid[g,:] @ W2[e] + b2[e]) ----------
__global__ __launch_bounds__(256) void k_moe_ff2(const float* __restrict__ hid,
                                                 const float* __restrict__ W2,
                                                 const float* __restrict__ b2,
                                                 float* __restrict__ x,
                                                 const int* __restrict__ perm,
                                                 const int* __restrict__ seg,
                                                 const float* __restrict__ topw){
  int e = blockIdx.z;
  int s0 = seg[e], cnt = seg[e + 1] - s0;
  int row0 = blockIdx.y * 64;
  if (row0 >= cnt) return;
  const float* Bp = W2 + (size_t)e * FF_ * D_;
  const float* bp = b2 + (size_t)e * D_;
  __shared__ float As[16][68];
  __shared__ float Bs[16][68];
  const int tid = threadIdx.x;
  const int ty = tid >> 4, tx = tid & 15;
  const int lam = tid >> 2, lak = (tid & 3) << 2;
  const int lbk = tid >> 4, lbn = (tid & 15) << 2;
  const int col0 = blockIdx.x * 64;
  float acc[4][4] = {};
  int ra = row0 + lam;
  const float* Arow = (ra < cnt) ? (hid + (size_t)(s0 + ra) * FF_) : nullptr;
  for (int k0 = 0; k0 < FF_; k0 += 16){
    float4 av = make_float4(0.f, 0.f, 0.f, 0.f);
    if (Arow) av = *reinterpret_cast<const float4*>(Arow + k0 + lak);
    As[lak + 0][lam] = av.x; As[lak + 1][lam] = av.y;
    As[lak + 2][lam] = av.z; As[lak + 3][lam] = av.w;
    *reinterpret_cast<float4*>(&Bs[lbk][lbn]) =
        *reinterpret_cast<const float4*>(Bp + (size_t)(k0 + lbk) * D_ + col0 + lbn);
    __syncthreads();
#pragma unroll
    for (int kk = 0; kk < 16; kk++){
      const float4 a = *reinterpret_cast<const float4*>(&As[kk][ty << 2]);
      const float4 b = *reinterpret_cast<const float4*>(&Bs[kk][tx << 2]);
      const float ar[4] = {a.x, a.y, a.z, a.w};
      const float br[4] = {b.x, b.y, b.z, b.w};
#pragma unroll
      for (int i = 0; i < 4; i++)
#pragma unroll
        for (int j = 0; j < 4; j++) acc[i][j] = fmaf(ar[i], br[j], acc[i][j]);
    }
    __syncthreads();
  }
  const int c0 = col0 + (tx << 2);
  float4 bv = *reinterpret_cast<const float4*>(bp + c0);
#pragma unroll
  for (int i = 0; i < 4; i++){
    int r = row0 + (ty << 2) + i;
    if (r < cnt){
      int t = perm[s0 + r];
      float w = topw[t];
      float* xr = x + (size_t)t * D_ + c0;
      float4 xv = *reinterpret_cast<const float4*>(xr);
      xv.x += w * (acc[i][0] + bv.x); xv.y += w * (acc[i][1] + bv.y);
      xv.z += w * (acc[i][2] + bv.z); xv.w += w * (acc[i][3] + bv.w);
      *reinterpret_cast<float4*>(xr) = xv;
    }
  }
}

// ======================= host launcher =======================
extern "C" void kernel_launch(void* const* d_in, const int* in_sizes, int n_in,
                              void* d_out, int out_size, void* d_ws, size_t ws_size,
                              hipStream_t stream){
  const int*   ids  = (const int*)  d_in[0];
  const float* tok  = (const float*)d_in[1];
  const float* pos  = (const float*)d_in[2];
  const float* Wqkv = (const float*)d_in[3];
  const float* bqkv = (const float*)d_in[4];
  const float* Wo   = (const float*)d_in[5];
  const float* bo   = (const float*)d_in[6];
  const float* rW   = (const float*)d_in[7];
  const float* rb   = (const float*)d_in[8];
  const float* eW1  = (const float*)d_in[9];
  const float* eb1  = (const float*)d_in[10];
  const float* eW2  = (const float*)d_in[11];
  const float* eb2  = (const float*)d_in[12];
  const float* n1w  = (const float*)d_in[13];
  const float* n2w  = (const float*)d_in[14];
  const float* noww = (const float*)d_in[15];
  const float* lmW  = (const float*)d_in[16];

  float* out    = (float*)d_out;
  float* logits = out;                             // [T,V]
  float* aux    = out + (size_t)T_ * V_;           // [1]
  float* rlog   = aux + 1;                         // [L,T,E]

  float* ws = (float*)d_ws;
  size_t off = 0;
  float* x     = ws + off; off += (size_t)T_ * D_;
  float* h     = ws + off; off += (size_t)T_ * D_;
  float* qkv   = ws + off; off += (size_t)T_ * D3_;
  float* attno = ws + off; off += (size_t)T_ * D_;
  float* hid   = ws + off; off += (size_t)T_ * FF_;
  float* topw  = ws + off; off += T_;
  float* psum  = ws + off; off += E_;
  int* counts  = (int*)(ws + off); off += E_;
  int* topi    = (int*)(ws + off); off += T_;
  int* perm    = (int*)(ws + off); off += T_;
  int* seg     = (int*)(ws + off); off += (E_ + 1);
  int* cursor  = (int*)(ws + off); off += E_;

  hipMemsetAsync(aux, 0, sizeof(float), stream);
  k_embed<<<T_, 256, 0, stream>>>(ids, tok, pos, x);

  for (int l = 0; l < L_; l++){
    // --- attention block ---
    k_rmsnorm<<<T_, 256, 0, stream>>>(x, n1w + (size_t)l * D_, h);
    k_gemm<true, false><<<dim3(D3_ / 64, T_ / 64), 256, 0, stream>>>(
        h, Wqkv + (size_t)l * D_ * D3_, bqkv + (size_t)l * D3_, qkv, T_, D3_, D_);
    k_attn2<<<B_ * H_ * (S_ / 8), 256, 0, stream>>>(qkv, attno);
    k_gemm<true, true><<<dim3(D_ / 64, T_ / 64), 256, 0, stream>>>(
        attno, Wo + (size_t)l * D_ * D_, bo + (size_t)l * D_, x, T_, D_, D_);
    // --- MoE block ---
    k_rmsnorm<<<T_, 256, 0, stream>>>(x, n2w + (size_t)l * D_, h);
    hipMemsetAsync(psum, 0, 2 * E_ * sizeof(float), stream);   // psum + counts
    k_router<<<T_, 64, 0, stream>>>(h, rW + (size_t)l * D_ * E_, rb + (size_t)l * E_,
                                    rlog + (size_t)l * T_ * E_, topw, topi, counts, psum);
    k_route_fin<<<1, 64, 0, stream>>>(counts, psum, seg, cursor, aux);
    k_scatter<<<T_ / 256, 256, 0, stream>>>(topi, cursor, perm);
    k_moe_ff1<<<dim3(FF_ / 64, T_ / 64, E_), 256, 0, stream>>>(
        h, eW1 + (size_t)l * E_ * D_ * FF_, eb1 + (size_t)l * E_ * FF_, hid, perm, seg);
    k_moe_ff2<<<dim3(D_ / 64, T_ / 64, E_), 256, 0, stream>>>(
        hid, eW2 + (size_t)l * E_ * FF_ * D_, eb2 + (size_t)l * E_ * D_, x, perm, seg, topw);
  }

  // --- final norm + LM head ---
  k_rmsnorm<<<T_, 256, 0, stream>>>(x, noww, h);
  k_gemm<false, false><<<dim3(V_ / 64, T_ / 64), 256, 0, stream>>>(
      h, lmW, nullptr, logits, T_, V_, D_);
}

// Round 3
// 7803.833 us; speedup vs baseline: 2.5301x; 1.6804x over previous
//
#include <hip/hip_runtime.h>

// ==== model dims (fixed by the reference) ====
constexpr int B_  = 2, S_ = 1024, T_ = 2048;   // T = B*S tokens
constexpr int D_  = 512, H_ = 8, DH_ = 64;
constexpr int L_  = 12, E_ = 8, FF_ = 2048;
constexpr int V_  = 32000, D3_ = 1536;

using half8_t = __attribute__((ext_vector_type(8))) _Float16;
using half4_t = __attribute__((ext_vector_type(4))) _Float16;
using half2_t = __attribute__((ext_vector_type(2))) _Float16;
using f32x4_t = __attribute__((ext_vector_type(4))) float;

// ---------- helpers ----------
__device__ __forceinline__ float wred(float v){
#pragma unroll
  for (int off = 32; off; off >>= 1) v += __shfl_xor(v, off);
  return v;
}
__device__ __forceinline__ float wredmax(float v){
#pragma unroll
  for (int off = 32; off; off >>= 1) v = fmaxf(v, __shfl_xor(v, off));
  return v;
}
__device__ __forceinline__ float gelu_f(float v){
  return 0.5f * v * (1.f + erff(v * 0.70710678118654752f));
}

// ---------- embedding ----------
__global__ void k_embed(const int* __restrict__ ids, const float* __restrict__ tok,
                        const float* __restrict__ pos, float* __restrict__ x){
  int t = blockIdx.x;
  int s = t & (S_ - 1);
  int id = ids[t];
  const float* tr = tok + (size_t)id * D_;
  const float* pr = pos + (size_t)s  * D_;
  float* xr = x + (size_t)t * D_;
  for (int d = threadIdx.x; d < D_; d += blockDim.x) xr[d] = tr[d] + pr[d];
}

// ---------- rmsnorm ----------
__global__ __launch_bounds__(256) void k_rmsnorm(const float* __restrict__ x,
                                                 const float* __restrict__ w,
                                                 float* __restrict__ h){
  int t = blockIdx.x;
  const float* xr = x + (size_t)t * D_;
  float* hr = h + (size_t)t * D_;
  float ss = 0.f;
  for (int d = threadIdx.x; d < D_; d += 256){ float v = xr[d]; ss += v * v; }
  ss = wred(ss);
  __shared__ float sp[4];
  __shared__ float sscale;
  if ((threadIdx.x & 63) == 0) sp[threadIdx.x >> 6] = ss;
  __syncthreads();
  if (threadIdx.x == 0){
    float tot = sp[0] + sp[1] + sp[2] + sp[3];
    sscale = rsqrtf(tot / (float)D_ + 1e-6f);
  }
  __syncthreads();
  float sc = sscale;
  for (int d = threadIdx.x; d < D_; d += 256) hr[d] = xr[d] * sc * w[d];
}

// ======================================================================
// MFMA GEMM with fp16x2 split (3 products, fp32-grade precision) or
// single f16-hi product (NPROD=1, for the LM head).
// C[M,N] = A[M,K] @ B[K,N], A/B/C fp32 in global.
// 256 thr / 4 waves (2x2), BK=32, LDS tiles [rows][40] f16 (pad for banks
// + 16B-aligned b128 frag reads). Lo-parts pre-scaled by 2^11 (f16 denorm
// dodge), recombined as hh + mix/2048.
// EPI: 0=bias+store 1=bias+acc 2=bias+gelu+store(MoE hid) 3=moe scaled acc 4=store
// ======================================================================
template<int BM, int BN, int NPROD, int EPI, bool MOE, bool APERM, bool SWAPXY>
__global__ __launch_bounds__(256) void k_mgemm(
    const float* __restrict__ A, const float* __restrict__ Bm,
    const float* __restrict__ bias, float* __restrict__ C,
    int M, int N, int K,
    const int* __restrict__ seg, const int* __restrict__ perm,
    const float* __restrict__ topw){
  constexpr int FM = BM / 32, FN = BN / 32;
  const int tid = threadIdx.x;
  const int colTile = SWAPXY ? blockIdx.y : blockIdx.x;
  const int rowTile = SWAPXY ? blockIdx.x : blockIdx.y;
  int e = 0, s0 = 0, cnt = M;
  if (MOE){ e = blockIdx.z; s0 = seg[e]; cnt = seg[e + 1] - s0; }
  const int row0 = rowTile * BM, col0 = colTile * BN;
  if (MOE && row0 >= cnt) return;
  const float* Bp = Bm + (size_t)e * K * N;
  const float* bp = bias + (size_t)e * N;

  __shared__ _Float16 Ah[BM][40];
  __shared__ _Float16 Al[NPROD == 3 ? BM : 1][40];
  __shared__ _Float16 Bh[BN][40];
  __shared__ _Float16 Bl[NPROD == 3 ? BN : 1][40];

  // A loader assignment
  const int am = (BM == 64) ? (tid >> 2) : (tid >> 1);
  const int ak = (BM == 64) ? ((tid & 3) << 3) : ((tid & 1) << 4);
  const int agrow = row0 + am;
  const bool aval = agrow < cnt;
  const float* Arow = nullptr;
  if (aval){
    int ridx = APERM ? perm[s0 + agrow] : (MOE ? s0 + agrow : agrow);
    Arow = A + (size_t)ridx * K;
  }
  // B loader assignment
  const int bn = (BN == 128) ? ((tid & 31) << 2) : ((tid & 15) << 2);
  const int bpair0 = (BN == 128) ? (tid >> 5) : (tid >> 4);

  const int lane = tid & 63, w = tid >> 6;
  const int wm0 = (w >> 1) * (BM / 2), wn0 = (w & 1) * (BN / 2);
  const int lr = lane & 15, kg = lane >> 4;

  f32x4_t acc_hh[FM][FN];
  f32x4_t acc_mx[NPROD == 3 ? FM : 1][NPROD == 3 ? FN : 1];
#pragma unroll
  for (int i = 0; i < FM; i++)
#pragma unroll
    for (int j = 0; j < FN; j++){
      acc_hh[i][j] = (f32x4_t){0.f, 0.f, 0.f, 0.f};
      if (NPROD == 3) acc_mx[i][j] = (f32x4_t){0.f, 0.f, 0.f, 0.f};
    }

  for (int k0 = 0; k0 < K; k0 += 32){
    // ---- stage A ----
    constexpr int NAQ = (BM == 64) ? 2 : 4;
#pragma unroll
    for (int q = 0; q < NAQ; q++){
      float4 av = make_float4(0.f, 0.f, 0.f, 0.f);
      if (aval) av = *reinterpret_cast<const float4*>(Arow + k0 + ak + (q << 2));
      const float a4[4] = {av.x, av.y, av.z, av.w};
      half4_t hi, lo;
#pragma unroll
      for (int u = 0; u < 4; u++){
        hi[u] = (_Float16)a4[u];
        if (NPROD == 3) lo[u] = (_Float16)((a4[u] - (float)hi[u]) * 2048.f);
      }
      *reinterpret_cast<half4_t*>(&Ah[am][ak + (q << 2)]) = hi;
      if (NPROD == 3) *reinterpret_cast<half4_t*>(&Al[am][ak + (q << 2)]) = lo;
    }
    // ---- stage B ----
    constexpr int NBI = (BN == 128) ? 2 : 1;
#pragma unroll
    for (int it = 0; it < NBI; it++){
      const int p = bpair0 + it * 8;
      const int kk = p << 1;
      const float4 b0 = *reinterpret_cast<const float4*>(Bp + (size_t)(k0 + kk) * N + col0 + bn);
      const float4 b1 = *reinterpret_cast<const float4*>(Bp + (size_t)(k0 + kk + 1) * N + col0 + bn);
      const float b0a[4] = {b0.x, b0.y, b0.z, b0.w};
      const float b1a[4] = {b1.x, b1.y, b1.z, b1.w};
#pragma unroll
      for (int j = 0; j < 4; j++){
        _Float16 h0 = (_Float16)b0a[j], h1 = (_Float16)b1a[j];
        *reinterpret_cast<half2_t*>(&Bh[bn + j][kk]) = (half2_t){h0, h1};
        if (NPROD == 3){
          _Float16 l0 = (_Float16)((b0a[j] - (float)h0) * 2048.f);
          _Float16 l1 = (_Float16)((b1a[j] - (float)h1) * 2048.f);
          *reinterpret_cast<half2_t*>(&Bl[bn + j][kk]) = (half2_t){l0, l1};
        }
      }
    }
    __syncthreads();
    // ---- fragments + MFMA ----
    half8_t fAh[FM], fBh[FN];
    half8_t fAl[NPROD == 3 ? FM : 1], fBl[NPROD == 3 ? FN : 1];
#pragma unroll
    for (int fm = 0; fm < FM; fm++){
      const int r = wm0 + fm * 16 + lr;
      fAh[fm] = *reinterpret_cast<const half8_t*>(&Ah[r][kg << 3]);
      if (NPROD == 3) fAl[fm] = *reinterpret_cast<const half8_t*>(&Al[r][kg << 3]);
    }
#pragma unroll
    for (int fn = 0; fn < FN; fn++){
      const int c = wn0 + fn * 16 + lr;
      fBh[fn] = *reinterpret_cast<const half8_t*>(&Bh[c][kg << 3]);
      if (NPROD == 3) fBl[fn] = *reinterpret_cast<const half8_t*>(&Bl[c][kg << 3]);
    }
#pragma unroll
    for (int fm = 0; fm < FM; fm++)
#pragma unroll
      for (int fn = 0; fn < FN; fn++){
        acc_hh[fm][fn] = __builtin_amdgcn_mfma_f32_16x16x32_f16(
            fAh[fm], fBh[fn], acc_hh[fm][fn], 0, 0, 0);
        if (NPROD == 3){
          acc_mx[fm][fn] = __builtin_amdgcn_mfma_f32_16x16x32_f16(
              fAh[fm], fBl[fn], acc_mx[fm][fn], 0, 0, 0);
          acc_mx[fm][fn] = __builtin_amdgcn_mfma_f32_16x16x32_f16(
              fAl[fm], fBh[fn], acc_mx[fm][fn], 0, 0, 0);
        }
      }
    __syncthreads();
  }

  // ---- epilogue ----
#pragma unroll
  for (int fm = 0; fm < FM; fm++){
#pragma unroll
    for (int reg = 0; reg < 4; reg++){
      const int grow = row0 + wm0 + fm * 16 + (kg << 2) + reg;
      if (grow >= cnt) continue;
      int trow = 0; float tw = 0.f;
      if (EPI == 3){ trow = perm[s0 + grow]; tw = topw[trow]; }
#pragma unroll
      for (int fn = 0; fn < FN; fn++){
        const int col = col0 + wn0 + fn * 16 + lr;
        float v = acc_hh[fm][fn][reg];
        if (NPROD == 3) v += acc_mx[fm][fn][reg] * (1.f / 2048.f);
        if (EPI == 0){
          C[(size_t)grow * N + col] = v + bp[col];
        } else if (EPI == 1){
          C[(size_t)grow * N + col] += v + bp[col];
        } else if (EPI == 2){
          C[(size_t)(s0 + grow) * N + col] = gelu_f(v + bp[col]);
        } else if (EPI == 3){
          C[(size_t)trow * N + col] += tw * (v + bp[col]);
        } else {
          C[(size_t)grow * N + col] = v;
        }
      }
    }
  }
}

// ---------- causal attention v2 (unchanged, known-good) ----------
__global__ __launch_bounds__(256) void k_attn2(const float* __restrict__ qkv,
                                               float* __restrict__ o){
  __shared__ float Ks[64 * 64];
  __shared__ float Vt[64 * 64];
  __shared__ float ps[4][2][64];
  const int tid = threadIdx.x;
  const int w = tid >> 6, lane = tid & 63;
  const int bid = blockIdx.x;
  const int qb = bid & 127;
  const int h  = (bid >> 7) & 7;
  const int b  = bid >> 10;
  const int qbase = qb << 3;
  const int qr0 = qbase + (w << 1), qr1 = qr0 + 1;
  const size_t bbase = (size_t)(b << 10) * D3_;
  const int hoff = h * 64;
  float q0v = qkv[bbase + (size_t)qr0 * D3_ + hoff + lane] * 0.125f;
  float q1v = qkv[bbase + (size_t)qr1 * D3_ + hoff + lane] * 0.125f;
  float m0 = -1e30f, l0 = 0.f, a0 = 0.f;
  float m1 = -1e30f, l1 = 0.f, a1 = 0.f;
  const int nt = ((qbase + 7) >> 6) + 1;
  const int jr = tid >> 2, cg = tid & 3;
  for (int jt = 0; jt < nt; jt++){
    const int j0 = jt << 6;
    __syncthreads();
    const float* krow = qkv + bbase + (size_t)(j0 + jr) * D3_ + 512 + hoff;
#pragma unroll
    for (int cc = 0; cc < 4; cc++){
      const int c = cg + (cc << 2);
      const float4 kv4 = *reinterpret_cast<const float4*>(krow + (c << 2));
      *reinterpret_cast<float4*>(&Ks[(jr << 6) + ((c ^ (jr & 7)) << 2)]) = kv4;
      const float4 vv4 = *reinterpret_cast<const float4*>(krow + 512 + (c << 2));
      const int d0 = c << 2, jh = jr >> 2, jl = jr & 3;
      Vt[((d0 + 0) << 6) + ((jh ^ ((d0 + 0) & 7)) << 2) + jl] = vv4.x;
      Vt[((d0 + 1) << 6) + ((jh ^ ((d0 + 1) & 7)) << 2) + jl] = vv4.y;
      Vt[((d0 + 2) << 6) + ((jh ^ ((d0 + 2) & 7)) << 2) + jl] = vv4.z;
      Vt[((d0 + 3) << 6) + ((jh ^ ((d0 + 3) & 7)) << 2) + jl] = vv4.w;
    }
    __syncthreads();
    float s0 = 0.f, s1 = 0.f;
#pragma unroll
    for (int c = 0; c < 16; c++){
      const float4 kx = *reinterpret_cast<const float4*>(
          &Ks[(lane << 6) + ((c ^ (lane & 7)) << 2)]);
      const float kr[4] = {kx.x, kx.y, kx.z, kx.w};
#pragma unroll
      for (int u = 0; u < 4; u++){
        const int d = (c << 2) + u;
        s0 = fmaf(__shfl(q0v, d), kr[u], s0);
        s1 = fmaf(__shfl(q1v, d), kr[u], s1);
      }
    }
    const int jg = j0 + lane;
    const float s0m = (jg <= qr0) ? s0 : -1e30f;
    const float s1m = (jg <= qr1) ? s1 : -1e30f;
    const float mn0 = fmaxf(m0, wredmax(s0m));
    const float mn1 = fmaxf(m1, wredmax(s1m));
    const float p0 = __expf(s0m - mn0);
    const float p1 = __expf(s1m - mn1);
    const float cr0 = __expf(m0 - mn0);
    const float cr1 = __expf(m1 - mn1);
    l0 = l0 * cr0 + wred(p0);
    l1 = l1 * cr1 + wred(p1);
    a0 *= cr0; a1 *= cr1;
    m0 = mn0; m1 = mn1;
    ps[w][0][lane] = p0;
    ps[w][1][lane] = p1;
#pragma unroll
    for (int c = 0; c < 16; c++){
      const float4 vx = *reinterpret_cast<const float4*>(
          &Vt[(lane << 6) + ((c ^ (lane & 7)) << 2)]);
      const float4 p0v = *reinterpret_cast<const float4*>(&ps[w][0][c << 2]);
      const float4 p1v = *reinterpret_cast<const float4*>(&ps[w][1][c << 2]);
      a0 = fmaf(p0v.x, vx.x, a0); a0 = fmaf(p0v.y, vx.y, a0);
      a0 = fmaf(p0v.z, vx.z, a0); a0 = fmaf(p0v.w, vx.w, a0);
      a1 = fmaf(p1v.x, vx.x, a1); a1 = fmaf(p1v.y, vx.y, a1);
      a1 = fmaf(p1v.z, vx.z, a1); a1 = fmaf(p1v.w, vx.w, a1);
    }
  }
  const int t0 = (b << 10) + qr0;
  o[(size_t)t0 * D_ + hoff + lane]       = a0 / l0;
  o[(size_t)(t0 + 1) * D_ + hoff + lane] = a1 / l1;
}

// ---------- router: logits, softmax, top-1 (NO global atomics) ----------
__global__ __launch_bounds__(64) void k_router(const float* __restrict__ h2,
                                               const float* __restrict__ rW,
                                               const float* __restrict__ rb,
                                               float* __restrict__ rl_out,
                                               float* __restrict__ topw,
                                               int* __restrict__ topi){
  int t = blockIdx.x, lane = threadIdx.x;
  const float* hr = h2 + (size_t)t * D_;
  float acc[8] = {0,0,0,0,0,0,0,0};
  for (int d = lane; d < D_; d += 64){
    float hv = hr[d];
    const float* wr = rW + (size_t)d * E_;
    float4 w0 = *reinterpret_cast<const float4*>(wr);
    float4 w1 = *reinterpret_cast<const float4*>(wr + 4);
    acc[0] += hv * w0.x; acc[1] += hv * w0.y; acc[2] += hv * w0.z; acc[3] += hv * w0.w;
    acc[4] += hv * w1.x; acc[5] += hv * w1.y; acc[6] += hv * w1.z; acc[7] += hv * w1.w;
  }
  float rl[8];
#pragma unroll
  for (int e = 0; e < 8; e++) rl[e] = wred(acc[e]) + rb[e];
  float mx = rl[0];
#pragma unroll
  for (int e = 1; e < 8; e++) mx = fmaxf(mx, rl[e]);
  float p[8], s = 0.f;
#pragma unroll
  for (int e = 0; e < 8; e++){ p[e] = __expf(rl[e] - mx); s += p[e]; }
  float inv = 1.f / s;
  int arg = 0; float best = rl[0];
#pragma unroll
  for (int e = 1; e < 8; e++) if (rl[e] > best){ best = rl[e]; arg = e; }
  if (lane == 0){
#pragma unroll
    for (int e = 0; e < 8; e++) rl_out[(size_t)t * E_ + e] = rl[e];
    topw[t] = p[arg] * inv;
    topi[t] = arg;
  }
}

// ---------- single-wave routing scan: seg/perm/aux, no atomics ----------
__global__ __launch_bounds__(64) void k_route_scan(const int* __restrict__ topi,
                                                   const float* __restrict__ rl,
                                                   int* __restrict__ seg,
                                                   int* __restrict__ perm,
                                                   float* __restrict__ aux){
  const int lane = threadIdx.x;
  int c[8] = {0,0,0,0,0,0,0,0};
  for (int i = 0; i < 32; i++) c[topi[lane * 32 + i]]++;
  int base[8], tot[8];
#pragma unroll
  for (int e = 0; e < 8; e++){
    int inc = c[e];
#pragma unroll
    for (int off = 1; off < 64; off <<= 1){
      int n = __shfl_up(inc, off);
      if (lane >= off) inc += n;
    }
    base[e] = inc - c[e];
    tot[e] = __shfl(inc, 63);
  }
  int segv[9]; segv[0] = 0;
#pragma unroll
  for (int e = 0; e < 8; e++) segv[e + 1] = segv[e] + tot[e];
  if (lane < 9) seg[lane] = segv[lane];
  int cur[8];
#pragma unroll
  for (int e = 0; e < 8; e++) cur[e] = segv[e] + base[e];
  for (int i = 0; i < 32; i++){
    int t = lane * 32 + i;
    int e = topi[t];
    perm[cur[e]++] = t;
  }
  // psum for aux (recompute softmax from stored logits)
  float ps[8] = {0,0,0,0,0,0,0,0};
  for (int i = 0; i < 32; i++){
    const float* r = rl + (size_t)(lane * 32 + i) * E_;
    float v[8], mx = r[0];
#pragma unroll
    for (int e = 0; e < 8; e++) v[e] = r[e];
#pragma unroll
    for (int e = 1; e < 8; e++) mx = fmaxf(mx, v[e]);
    float s = 0.f;
#pragma unroll
    for (int e = 0; e < 8; e++){ v[e] = __expf(v[e] - mx); s += v[e]; }
    float is = 1.f / s;
#pragma unroll
    for (int e = 0; e < 8; e++) ps[e] += v[e] * is;
  }
  float av = 0.f;
#pragma unroll
  for (int e = 0; e < 8; e++){
    float pst = wred(ps[e]);
    av += (float)tot[e] * pst;
  }
  if (lane == 0) aux[0] += 8.f * av / ((float)T_ * (float)T_);
}

// ======================= host launcher =======================
extern "C" void kernel_launch(void* const* d_in, const int* in_sizes, int n_in,
                              void* d_out, int out_size, void* d_ws, size_t ws_size,
                              hipStream_t stream){
  const int*   ids  = (const int*)  d_in[0];
  const float* tok  = (const float*)d_in[1];
  const float* pos  = (const float*)d_in[2];
  const float* Wqkv = (const float*)d_in[3];
  const float* bqkv = (const float*)d_in[4];
  const float* Wo   = (const float*)d_in[5];
  const float* bo   = (const float*)d_in[6];
  const float* rW   = (const float*)d_in[7];
  const float* rb   = (const float*)d_in[8];
  const float* eW1  = (const float*)d_in[9];
  const float* eb1  = (const float*)d_in[10];
  const float* eW2  = (const float*)d_in[11];
  const float* eb2  = (const float*)d_in[12];
  const float* n1w  = (const float*)d_in[13];
  const float* n2w  = (const float*)d_in[14];
  const float* noww = (const float*)d_in[15];
  const float* lmW  = (const float*)d_in[16];

  float* out    = (float*)d_out;
  float* logits = out;                             // [T,V]
  float* aux    = out + (size_t)T_ * V_;           // [1]
  float* rlog   = aux + 1;                         // [L,T,E]

  float* ws = (float*)d_ws;
  size_t off = 0;
  float* x     = ws + off; off += (size_t)T_ * D_;
  float* h     = ws + off; off += (size_t)T_ * D_;
  float* qkv   = ws + off; off += (size_t)T_ * D3_;
  float* attno = ws + off; off += (size_t)T_ * D_;
  float* hid   = ws + off; off += (size_t)T_ * FF_;
  float* topw  = ws + off; off += T_;
  int* topi    = (int*)(ws + off); off += T_;
  int* perm    = (int*)(ws + off); off += T_;
  int* seg     = (int*)(ws + off); off += (E_ + 1);

  hipMemsetAsync(aux, 0, sizeof(float), stream);
  k_embed<<<T_, 256, 0, stream>>>(ids, tok, pos, x);

  for (int l = 0; l < L_; l++){
    // --- attention block ---
    k_rmsnorm<<<T_, 256, 0, stream>>>(x, n1w + (size_t)l * D_, h);
    k_mgemm<64, 128, 3, 0, false, false, false><<<dim3(D3_ / 128, T_ / 64), 256, 0, stream>>>(
        h, Wqkv + (size_t)l * D_ * D3_, bqkv + (size_t)l * D3_, qkv,
        T_, D3_, D_, seg, perm, topw);
    k_attn2<<<B_ * H_ * (S_ / 8), 256, 0, stream>>>(qkv, attno);
    k_mgemm<64, 64, 3, 1, false, false, false><<<dim3(D_ / 64, T_ / 64), 256, 0, stream>>>(
        attno, Wo + (size_t)l * D_ * D_, bo + (size_t)l * D_, x,
        T_, D_, D_, seg, perm, topw);
    // --- MoE block ---
    k_rmsnorm<<<T_, 256, 0, stream>>>(x, n2w + (size_t)l * D_, h);
    k_router<<<T_, 64, 0, stream>>>(h, rW + (size_t)l * D_ * E_, rb + (size_t)l * E_,
                                    rlog + (size_t)l * T_ * E_, topw, topi);
    k_route_scan<<<1, 64, 0, stream>>>(topi, rlog + (size_t)l * T_ * E_, seg, perm, aux);
    k_mgemm<64, 128, 3, 2, true, true, false><<<dim3(FF_ / 128, T_ / 64, E_), 256, 0, stream>>>(
        h, eW1 + (size_t)l * E_ * D_ * FF_, eb1 + (size_t)l * E_ * FF_, hid,
        T_, FF_, D_, seg, perm, topw);
    k_mgemm<64, 64, 3, 3, true, false, false><<<dim3(D_ / 64, T_ / 64, E_), 256, 0, stream>>>(
        hid, eW2 + (size_t)l * E_ * FF_ * D_, eb2 + (size_t)l * E_ * D_, x,
        T_, D_, FF_, seg, perm, topw);
  }

  // --- final norm + LM head (f16-hi single product; M-fastest grid for L2) ---
  k_rmsnorm<<<T_, 256, 0, stream>>>(x, noww, h);
  k_mgemm<128, 128, 1, 4, false, false, true><<<dim3(T_ / 128, V_ / 128), 256, 0, stream>>>(
      h, lmW, noww /*unused*/, logits, T_, V_, D_, seg, perm, topw);
}

// Round 4
// 6533.314 us; speedup vs baseline: 3.0221x; 1.1945x over previous
//
#include <hip/hip_runtime.h>

// ==== model dims (fixed by the reference) ====
constexpr int B_  = 2, S_ = 1024, T_ = 2048;   // T = B*S tokens
constexpr int D_  = 512, H_ = 8, DH_ = 64;
constexpr int L_  = 12, E_ = 8, FF_ = 2048;
constexpr int V_  = 32000, D3_ = 1536;

using half8_t = __attribute__((ext_vector_type(8))) _Float16;
using half4_t = __attribute__((ext_vector_type(4))) _Float16;
using half2_t = __attribute__((ext_vector_type(2))) _Float16;
using f32x4_t = __attribute__((ext_vector_type(4))) float;

// ---------- helpers ----------
__device__ __forceinline__ float wred(float v){
#pragma unroll
  for (int off = 32; off; off >>= 1) v += __shfl_xor(v, off);
  return v;
}
__device__ __forceinline__ float wredmax(float v){
#pragma unroll
  for (int off = 32; off; off >>= 1) v = fmaxf(v, __shfl_xor(v, off));
  return v;
}
__device__ __forceinline__ float gelu_f(float v){
  return 0.5f * v * (1.f + erff(v * 0.70710678118654752f));
}

// ---------- embedding ----------
__global__ void k_embed(const int* __restrict__ ids, const float* __restrict__ tok,
                        const float* __restrict__ pos, float* __restrict__ x){
  int t = blockIdx.x;
  int s = t & (S_ - 1);
  int id = ids[t];
  const float* tr = tok + (size_t)id * D_;
  const float* pr = pos + (size_t)s  * D_;
  float* xr = x + (size_t)t * D_;
  for (int d = threadIdx.x; d < D_; d += blockDim.x) xr[d] = tr[d] + pr[d];
}

// ---------- rmsnorm ----------
__global__ __launch_bounds__(256) void k_rmsnorm(const float* __restrict__ x,
                                                 const float* __restrict__ w,
                                                 float* __restrict__ h){
  int t = blockIdx.x;
  const float* xr = x + (size_t)t * D_;
  float* hr = h + (size_t)t * D_;
  float ss = 0.f;
  for (int d = threadIdx.x; d < D_; d += 256){ float v = xr[d]; ss += v * v; }
  ss = wred(ss);
  __shared__ float sp[4];
  __shared__ float sscale;
  if ((threadIdx.x & 63) == 0) sp[threadIdx.x >> 6] = ss;
  __syncthreads();
  if (threadIdx.x == 0){
    float tot = sp[0] + sp[1] + sp[2] + sp[3];
    sscale = rsqrtf(tot / (float)D_ + 1e-6f);
  }
  __syncthreads();
  float sc = sscale;
  for (int d = threadIdx.x; d < D_; d += 256) hr[d] = xr[d] * sc * w[d];
}

// ======================================================================
// MFMA GEMM with fp16x2 split (3 products) or single f16-hi (NPROD=1).
// EPI: 0=bias+store 1=bias+acc 2=bias+gelu+store(MoE hid) 3=moe scaled acc 4=store
// ======================================================================
template<int BM, int BN, int NPROD, int EPI, bool MOE, bool APERM, bool SWAPXY>
__global__ __launch_bounds__(256) void k_mgemm(
    const float* __restrict__ A, const float* __restrict__ Bm,
    const float* __restrict__ bias, float* __restrict__ C,
    int M, int N, int K,
    const int* __restrict__ seg, const int* __restrict__ perm,
    const float* __restrict__ topw){
  constexpr int FM = BM / 32, FN = BN / 32;
  const int tid = threadIdx.x;
  const int colTile = SWAPXY ? blockIdx.y : blockIdx.x;
  const int rowTile = SWAPXY ? blockIdx.x : blockIdx.y;
  int e = 0, s0 = 0, cnt = M;
  if (MOE){ e = blockIdx.z; s0 = seg[e]; cnt = seg[e + 1] - s0; }
  const int row0 = rowTile * BM, col0 = colTile * BN;
  if (MOE && row0 >= cnt) return;
  const float* Bp = Bm + (size_t)e * K * N;
  const float* bp = bias + (size_t)e * N;

  __shared__ _Float16 Ah[BM][40];
  __shared__ _Float16 Al[NPROD == 3 ? BM : 1][40];
  __shared__ _Float16 Bh[BN][40];
  __shared__ _Float16 Bl[NPROD == 3 ? BN : 1][40];

  const int am = (BM == 64) ? (tid >> 2) : (tid >> 1);
  const int ak = (BM == 64) ? ((tid & 3) << 3) : ((tid & 1) << 4);
  const int agrow = row0 + am;
  const bool aval = agrow < cnt;
  const float* Arow = nullptr;
  if (aval){
    int ridx = APERM ? perm[s0 + agrow] : (MOE ? s0 + agrow : agrow);
    Arow = A + (size_t)ridx * K;
  }
  const int bn = (BN == 128) ? ((tid & 31) << 2) : ((tid & 15) << 2);
  const int bpair0 = (BN == 128) ? (tid >> 5) : (tid >> 4);

  const int lane = tid & 63, w = tid >> 6;
  const int wm0 = (w >> 1) * (BM / 2), wn0 = (w & 1) * (BN / 2);
  const int lr = lane & 15, kg = lane >> 4;

  f32x4_t acc_hh[FM][FN];
  f32x4_t acc_mx[NPROD == 3 ? FM : 1][NPROD == 3 ? FN : 1];
#pragma unroll
  for (int i = 0; i < FM; i++)
#pragma unroll
    for (int j = 0; j < FN; j++){
      acc_hh[i][j] = (f32x4_t){0.f, 0.f, 0.f, 0.f};
      if (NPROD == 3) acc_mx[i][j] = (f32x4_t){0.f, 0.f, 0.f, 0.f};
    }

  for (int k0 = 0; k0 < K; k0 += 32){
    constexpr int NAQ = (BM == 64) ? 2 : 4;
#pragma unroll
    for (int q = 0; q < NAQ; q++){
      float4 av = make_float4(0.f, 0.f, 0.f, 0.f);
      if (aval) av = *reinterpret_cast<const float4*>(Arow + k0 + ak + (q << 2));
      const float a4[4] = {av.x, av.y, av.z, av.w};
      half4_t hi, lo;
#pragma unroll
      for (int u = 0; u < 4; u++){
        hi[u] = (_Float16)a4[u];
        if (NPROD == 3) lo[u] = (_Float16)((a4[u] - (float)hi[u]) * 2048.f);
      }
      *reinterpret_cast<half4_t*>(&Ah[am][ak + (q << 2)]) = hi;
      if (NPROD == 3) *reinterpret_cast<half4_t*>(&Al[am][ak + (q << 2)]) = lo;
    }
    constexpr int NBI = (BN == 128) ? 2 : 1;
#pragma unroll
    for (int it = 0; it < NBI; it++){
      const int p = bpair0 + it * 8;
      const int kk = p << 1;
      const float4 b0 = *reinterpret_cast<const float4*>(Bp + (size_t)(k0 + kk) * N + col0 + bn);
      const float4 b1 = *reinterpret_cast<const float4*>(Bp + (size_t)(k0 + kk + 1) * N + col0 + bn);
      const float b0a[4] = {b0.x, b0.y, b0.z, b0.w};
      const float b1a[4] = {b1.x, b1.y, b1.z, b1.w};
#pragma unroll
      for (int j = 0; j < 4; j++){
        _Float16 h0 = (_Float16)b0a[j], h1 = (_Float16)b1a[j];
        *reinterpret_cast<half2_t*>(&Bh[bn + j][kk]) = (half2_t){h0, h1};
        if (NPROD == 3){
          _Float16 l0 = (_Float16)((b0a[j] - (float)h0) * 2048.f);
          _Float16 l1 = (_Float16)((b1a[j] - (float)h1) * 2048.f);
          *reinterpret_cast<half2_t*>(&Bl[bn + j][kk]) = (half2_t){l0, l1};
        }
      }
    }
    __syncthreads();
    half8_t fAh[FM], fBh[FN];
    half8_t fAl[NPROD == 3 ? FM : 1], fBl[NPROD == 3 ? FN : 1];
#pragma unroll
    for (int fm = 0; fm < FM; fm++){
      const int r = wm0 + fm * 16 + lr;
      fAh[fm] = *reinterpret_cast<const half8_t*>(&Ah[r][kg << 3]);
      if (NPROD == 3) fAl[fm] = *reinterpret_cast<const half8_t*>(&Al[r][kg << 3]);
    }
#pragma unroll
    for (int fn = 0; fn < FN; fn++){
      const int c = wn0 + fn * 16 + lr;
      fBh[fn] = *reinterpret_cast<const half8_t*>(&Bh[c][kg << 3]);
      if (NPROD == 3) fBl[fn] = *reinterpret_cast<const half8_t*>(&Bl[c][kg << 3]);
    }
#pragma unroll
    for (int fm = 0; fm < FM; fm++)
#pragma unroll
      for (int fn = 0; fn < FN; fn++){
        acc_hh[fm][fn] = __builtin_amdgcn_mfma_f32_16x16x32_f16(
            fAh[fm], fBh[fn], acc_hh[fm][fn], 0, 0, 0);
        if (NPROD == 3){
          acc_mx[fm][fn] = __builtin_amdgcn_mfma_f32_16x16x32_f16(
              fAh[fm], fBl[fn], acc_mx[fm][fn], 0, 0, 0);
          acc_mx[fm][fn] = __builtin_amdgcn_mfma_f32_16x16x32_f16(
              fAl[fm], fBh[fn], acc_mx[fm][fn], 0, 0, 0);
        }
      }
    __syncthreads();
  }

#pragma unroll
  for (int fm = 0; fm < FM; fm++){
#pragma unroll
    for (int reg = 0; reg < 4; reg++){
      const int grow = row0 + wm0 + fm * 16 + (kg << 2) + reg;
      if (grow >= cnt) continue;
      int trow = 0; float tw = 0.f;
      if (EPI == 3){ trow = perm[s0 + grow]; tw = topw[trow]; }
#pragma unroll
      for (int fn = 0; fn < FN; fn++){
        const int col = col0 + wn0 + fn * 16 + lr;
        float v = acc_hh[fm][fn][reg];
        if (NPROD == 3) v += acc_mx[fm][fn][reg] * (1.f / 2048.f);
        if (EPI == 0){
          C[(size_t)grow * N + col] = v + bp[col];
        } else if (EPI == 1){
          C[(size_t)grow * N + col] += v + bp[col];
        } else if (EPI == 2){
          C[(size_t)(s0 + grow) * N + col] = gelu_f(v + bp[col]);
        } else if (EPI == 3){
          C[(size_t)trow * N + col] += tw * (v + bp[col]);
        } else {
          C[(size_t)grow * N + col] = v;
        }
      }
    }
  }
}

// ---------- causal attention v3: tiled flash-style, fp32 VALU ----------
// vs v2: q staged in LDS (broadcast reads replace 128 shfl/tile), 4-way
// partial accumulators (chain 64->16), deferred per-lane l reduction,
// bit-reversed q-block index for tail balance.
__global__ __launch_bounds__(256) void k_attn3(const float* __restrict__ qkv,
                                               float* __restrict__ o){
  __shared__ float Ks[64 * 64];
  __shared__ float Vt[64 * 64];
  __shared__ float qs[8][64];
  __shared__ float ps[4][2][64];
  const int tid = threadIdx.x;
  const int w = tid >> 6, lane = tid & 63;
  const int bid = blockIdx.x;
  const int bh = bid & 15;                               // b,h fastest
  const int qb = (int)(__brev((unsigned)(bid >> 4)) >> 25);  // 7-bit reverse
  const int h = bh & 7, b = bh >> 3;
  const int qbase = qb << 3;
  const int qr0 = qbase + (w << 1), qr1 = qr0 + 1;
  const size_t bbase = (size_t)(b << 10) * D3_;
  const int hoff = h * 64;
  // stage q rows (scale 1/8 folded; exact pow2)
  {
    const int r0 = tid >> 6, d0 = tid & 63;
    qs[r0][d0] = qkv[bbase + (size_t)(qbase + r0) * D3_ + hoff + d0] * 0.125f;
    const int r1 = (tid + 256) >> 6, d1 = tid & 63;
    qs[r1][d1] = qkv[bbase + (size_t)(qbase + r1) * D3_ + hoff + d1] * 0.125f;
  }
  float m0 = -1e30f, m1 = -1e30f;
  float l0 = 0.f, l1 = 0.f;                 // per-lane, reduced once at end
  float a0p0 = 0.f, a0p1 = 0.f, a0p2 = 0.f, a0p3 = 0.f;
  float a1p0 = 0.f, a1p1 = 0.f, a1p2 = 0.f, a1p3 = 0.f;
  const int nt = ((qbase + 7) >> 6) + 1;
  const int jr = tid >> 2, cg = tid & 3;
  for (int jt = 0; jt < nt; jt++){
    const int j0 = jt << 6;
    __syncthreads();   // first pass also covers qs staging
    // ---- stage K (swizzled row-major) and V (swizzled transposed) ----
    const float* krow = qkv + bbase + (size_t)(j0 + jr) * D3_ + 512 + hoff;
#pragma unroll
    for (int cc = 0; cc < 4; cc++){
      const int c = cg + (cc << 2);
      const float4 kv4 = *reinterpret_cast<const float4*>(krow + (c << 2));
      *reinterpret_cast<float4*>(&Ks[(jr << 6) + ((c ^ (jr & 7)) << 2)]) = kv4;
      const float4 vv4 = *reinterpret_cast<const float4*>(krow + 512 + (c << 2));
      const int d0 = c << 2, jh = jr >> 2, jl = jr & 3;
      Vt[((d0 + 0) << 6) + ((jh ^ ((d0 + 0) & 7)) << 2) + jl] = vv4.x;
      Vt[((d0 + 1) << 6) + ((jh ^ ((d0 + 1) & 7)) << 2) + jl] = vv4.y;
      Vt[((d0 + 2) << 6) + ((jh ^ ((d0 + 2) & 7)) << 2) + jl] = vv4.z;
      Vt[((d0 + 3) << 6) + ((jh ^ ((d0 + 3) & 7)) << 2) + jl] = vv4.w;
    }
    __syncthreads();
    // ---- scores: lane = key index, q via LDS broadcast ----
    float s0p0 = 0.f, s0p1 = 0.f, s0p2 = 0.f, s0p3 = 0.f;
    float s1p0 = 0.f, s1p1 = 0.f, s1p2 = 0.f, s1p3 = 0.f;
#pragma unroll
    for (int c = 0; c < 16; c++){
      const float4 kx = *reinterpret_cast<const float4*>(
          &Ks[(lane << 6) + ((c ^ (lane & 7)) << 2)]);
      const float4 q0c = *reinterpret_cast<const float4*>(&qs[w << 1][c << 2]);
      const float4 q1c = *reinterpret_cast<const float4*>(&qs[(w << 1) + 1][c << 2]);
      s0p0 = fmaf(q0c.x, kx.x, s0p0); s0p1 = fmaf(q0c.y, kx.y, s0p1);
      s0p2 = fmaf(q0c.z, kx.z, s0p2); s0p3 = fmaf(q0c.w, kx.w, s0p3);
      s1p0 = fmaf(q1c.x, kx.x, s1p0); s1p1 = fmaf(q1c.y, kx.y, s1p1);
      s1p2 = fmaf(q1c.z, kx.z, s1p2); s1p3 = fmaf(q1c.w, kx.w, s1p3);
    }
    const float s0 = (s0p0 + s0p1) + (s0p2 + s0p3);
    const float s1 = (s1p0 + s1p1) + (s1p2 + s1p3);
    // ---- online softmax ----
    const int jg = j0 + lane;
    const float s0m = (jg <= qr0) ? s0 : -1e30f;
    const float s1m = (jg <= qr1) ? s1 : -1e30f;
    const float mn0 = fmaxf(m0, wredmax(s0m));
    const float mn1 = fmaxf(m1, wredmax(s1m));
    const float p0 = __expf(s0m - mn0);
    const float p1 = __expf(s1m - mn1);
    const float cr0 = __expf(m0 - mn0);
    const float cr1 = __expf(m1 - mn1);
    l0 = l0 * cr0 + p0;
    l1 = l1 * cr1 + p1;
    a0p0 *= cr0; a0p1 *= cr0; a0p2 *= cr0; a0p3 *= cr0;
    a1p0 *= cr1; a1p1 *= cr1; a1p2 *= cr1; a1p3 *= cr1;
    m0 = mn0; m1 = mn1;
    ps[w][0][lane] = p0;
    ps[w][1][lane] = p1;
    // ---- PV: lane = output dim ----
#pragma unroll
    for (int c = 0; c < 16; c++){
      const float4 vx = *reinterpret_cast<const float4*>(
          &Vt[(lane << 6) + ((c ^ (lane & 7)) << 2)]);
      const float4 p0v = *reinterpret_cast<const float4*>(&ps[w][0][c << 2]);
      const float4 p1v = *reinterpret_cast<const float4*>(&ps[w][1][c << 2]);
      a0p0 = fmaf(p0v.x, vx.x, a0p0); a0p1 = fmaf(p0v.y, vx.y, a0p1);
      a0p2 = fmaf(p0v.z, vx.z, a0p2); a0p3 = fmaf(p0v.w, vx.w, a0p3);
      a1p0 = fmaf(p1v.x, vx.x, a1p0); a1p1 = fmaf(p1v.y, vx.y, a1p1);
      a1p2 = fmaf(p1v.z, vx.z, a1p2); a1p3 = fmaf(p1v.w, vx.w, a1p3);
    }
  }
  const float l0t = wred(l0);
  const float l1t = wred(l1);
  const int t0 = (b << 10) + qr0;
  o[(size_t)t0 * D_ + hoff + lane]       = ((a0p0 + a0p1) + (a0p2 + a0p3)) / l0t;
  o[(size_t)(t0 + 1) * D_ + hoff + lane] = ((a1p0 + a1p1) + (a1p2 + a1p3)) / l1t;
}

// ---------- router: logits, softmax, top-1 (no global atomics) ----------
__global__ __launch_bounds__(64) void k_router(const float* __restrict__ h2,
                                               const float* __restrict__ rW,
                                               const float* __restrict__ rb,
                                               float* __restrict__ rl_out,
                                               float* __restrict__ topw,
                                               int* __restrict__ topi){
  int t = blockIdx.x, lane = threadIdx.x;
  const float* hr = h2 + (size_t)t * D_;
  float acc[8] = {0,0,0,0,0,0,0,0};
  for (int d = lane; d < D_; d += 64){
    float hv = hr[d];
    const float* wr = rW + (size_t)d * E_;
    float4 w0 = *reinterpret_cast<const float4*>(wr);
    float4 w1 = *reinterpret_cast<const float4*>(wr + 4);
    acc[0] += hv * w0.x; acc[1] += hv * w0.y; acc[2] += hv * w0.z; acc[3] += hv * w0.w;
    acc[4] += hv * w1.x; acc[5] += hv * w1.y; acc[6] += hv * w1.z; acc[7] += hv * w1.w;
  }
  float rl[8];
#pragma unroll
  for (int e = 0; e < 8; e++) rl[e] = wred(acc[e]) + rb[e];
  float mx = rl[0];
#pragma unroll
  for (int e = 1; e < 8; e++) mx = fmaxf(mx, rl[e]);
  float p[8], s = 0.f;
#pragma unroll
  for (int e = 0; e < 8; e++){ p[e] = __expf(rl[e] - mx); s += p[e]; }
  float inv = 1.f / s;
  int arg = 0; float best = rl[0];
#pragma unroll
  for (int e = 1; e < 8; e++) if (rl[e] > best){ best = rl[e]; arg = e; }
  if (lane == 0){
#pragma unroll
    for (int e = 0; e < 8; e++) rl_out[(size_t)t * E_ + e] = rl[e];
    topw[t] = p[arg] * inv;
    topi[t] = arg;
  }
}

// ---------- single-wave routing scan: seg/perm/aux ----------
__global__ __launch_bounds__(64) void k_route_scan(const int* __restrict__ topi,
                                                   const float* __restrict__ rl,
                                                   int* __restrict__ seg,
                                                   int* __restrict__ perm,
                                                   float* __restrict__ aux){
  const int lane = threadIdx.x;
  int c[8] = {0,0,0,0,0,0,0,0};
  for (int i = 0; i < 32; i++) c[topi[lane * 32 + i]]++;
  int base[8], tot[8];
#pragma unroll
  for (int e = 0; e < 8; e++){
    int inc = c[e];
#pragma unroll
    for (int off = 1; off < 64; off <<= 1){
      int n = __shfl_up(inc, off);
      if (lane >= off) inc += n;
    }
    base[e] = inc - c[e];
    tot[e] = __shfl(inc, 63);
  }
  int segv[9]; segv[0] = 0;
#pragma unroll
  for (int e = 0; e < 8; e++) segv[e + 1] = segv[e] + tot[e];
  if (lane < 9) seg[lane] = segv[lane];
  int cur[8];
#pragma unroll
  for (int e = 0; e < 8; e++) cur[e] = segv[e] + base[e];
  for (int i = 0; i < 32; i++){
    int t = lane * 32 + i;
    int e = topi[t];
    perm[cur[e]++] = t;
  }
  float ps[8] = {0,0,0,0,0,0,0,0};
  for (int i = 0; i < 32; i++){
    const float* r = rl + (size_t)(lane * 32 + i) * E_;
    float v[8], mx = r[0];
#pragma unroll
    for (int e = 0; e < 8; e++) v[e] = r[e];
#pragma unroll
    for (int e = 1; e < 8; e++) mx = fmaxf(mx, v[e]);
    float s = 0.f;
#pragma unroll
    for (int e = 0; e < 8; e++){ v[e] = __expf(v[e] - mx); s += v[e]; }
    float is = 1.f / s;
#pragma unroll
    for (int e = 0; e < 8; e++) ps[e] += v[e] * is;
  }
  float av = 0.f;
#pragma unroll
  for (int e = 0; e < 8; e++){
    float pst = wred(ps[e]);
    av += (float)tot[e] * pst;
  }
  if (lane == 0) aux[0] += 8.f * av / ((float)T_ * (float)T_);
}

// ======================= host launcher =======================
extern "C" void kernel_launch(void* const* d_in, const int* in_sizes, int n_in,
                              void* d_out, int out_size, void* d_ws, size_t ws_size,
                              hipStream_t stream){
  const int*   ids  = (const int*)  d_in[0];
  const float* tok  = (const float*)d_in[1];
  const float* pos  = (const float*)d_in[2];
  const float* Wqkv = (const float*)d_in[3];
  const float* bqkv = (const float*)d_in[4];
  const float* Wo   = (const float*)d_in[5];
  const float* bo   = (const float*)d_in[6];
  const float* rW   = (const float*)d_in[7];
  const float* rb   = (const float*)d_in[8];
  const float* eW1  = (const float*)d_in[9];
  const float* eb1  = (const float*)d_in[10];
  const float* eW2  = (const float*)d_in[11];
  const float* eb2  = (const float*)d_in[12];
  const float* n1w  = (const float*)d_in[13];
  const float* n2w  = (const float*)d_in[14];
  const float* noww = (const float*)d_in[15];
  const float* lmW  = (const float*)d_in[16];

  float* out    = (float*)d_out;
  float* logits = out;                             // [T,V]
  float* aux    = out + (size_t)T_ * V_;           // [1]
  float* rlog   = aux + 1;                         // [L,T,E]

  float* ws = (float*)d_ws;
  size_t off = 0;
  float* x     = ws + off; off += (size_t)T_ * D_;
  float* h     = ws + off; off += (size_t)T_ * D_;
  float* qkv   = ws + off; off += (size_t)T_ * D3_;
  float* attno = ws + off; off += (size_t)T_ * D_;
  float* hid   = ws + off; off += (size_t)T_ * FF_;
  float* topw  = ws + off; off += T_;
  int* topi    = (int*)(ws + off); off += T_;
  int* perm    = (int*)(ws + off); off += T_;
  int* seg     = (int*)(ws + off); off += (E_ + 1);

  hipMemsetAsync(aux, 0, sizeof(float), stream);
  k_embed<<<T_, 256, 0, stream>>>(ids, tok, pos, x);

  for (int l = 0; l < L_; l++){
    // --- attention block ---
    k_rmsnorm<<<T_, 256, 0, stream>>>(x, n1w + (size_t)l * D_, h);
    k_mgemm<64, 128, 3, 0, false, false, false><<<dim3(D3_ / 128, T_ / 64), 256, 0, stream>>>(
        h, Wqkv + (size_t)l * D_ * D3_, bqkv + (size_t)l * D3_, qkv,
        T_, D3_, D_, seg, perm, topw);
    k_attn3<<<B_ * H_ * (S_ / 8), 256, 0, stream>>>(qkv, attno);
    k_mgemm<64, 64, 3, 1, false, false, false><<<dim3(D_ / 64, T_ / 64), 256, 0, stream>>>(
        attno, Wo + (size_t)l * D_ * D_, bo + (size_t)l * D_, x,
        T_, D_, D_, seg, perm, topw);
    // --- MoE block ---
    k_rmsnorm<<<T_, 256, 0, stream>>>(x, n2w + (size_t)l * D_, h);
    k_router<<<T_, 64, 0, stream>>>(h, rW + (size_t)l * D_ * E_, rb + (size_t)l * E_,
                                    rlog + (size_t)l * T_ * E_, topw, topi);
    k_route_scan<<<1, 64, 0, stream>>>(topi, rlog + (size_t)l * T_ * E_, seg, perm, aux);
    k_mgemm<64, 128, 3, 2, true, true, false><<<dim3(FF_ / 128, T_ / 64, E_), 256, 0, stream>>>(
        h, eW1 + (size_t)l * E_ * D_ * FF_, eb1 + (size_t)l * E_ * FF_, hid,
        T_, FF_, D_, seg, perm, topw);
    k_mgemm<64, 64, 3, 3, true, false, false><<<dim3(D_ / 64, T_ / 64, E_), 256, 0, stream>>>(
        hid, eW2 + (size_t)l * E_ * FF_ * D_, eb2 + (size_t)l * E_ * D_, x,
        T_, D_, FF_, seg, perm, topw);
  }

  // --- final norm + LM head (f16-hi single product; M-fastest grid for L2) ---
  k_rmsnorm<<<T_, 256, 0, stream>>>(x, noww, h);
  k_mgemm<128, 128, 1, 4, false, false, true><<<dim3(T_ / 128, V_ / 128), 256, 0, stream>>>(
      h, lmW, noww /*unused*/, logits, T_, V_, D_, seg, perm, topw);
}

// Round 5
// 4789.181 us; speedup vs baseline: 4.1227x; 1.3642x over previous
//
#include <hip/hip_runtime.h>

// ==== model dims (fixed by the reference) ====
constexpr int B_  = 2, S_ = 1024, T_ = 2048;   // T = B*S tokens
constexpr int D_  = 512, H_ = 8, DH_ = 64;
constexpr int L_  = 12, E_ = 8, FF_ = 2048;
constexpr int V_  = 32000, D3_ = 1536;

using half8_t = __attribute__((ext_vector_type(8))) _Float16;
using half2_t = __attribute__((ext_vector_type(2))) _Float16;
using f32x4_t = __attribute__((ext_vector_type(4))) float;

// ---------- helpers ----------
__device__ __forceinline__ float wred(float v){
#pragma unroll
  for (int off = 32; off; off >>= 1) v += __shfl_xor(v, off);
  return v;
}
__device__ __forceinline__ float wredmax(float v){
#pragma unroll
  for (int off = 32; off; off >>= 1) v = fmaxf(v, __shfl_xor(v, off));
  return v;
}
__device__ __forceinline__ float gelu_f(float v){
  return 0.5f * v * (1.f + erff(v * 0.70710678118654752f));
}

// ---------- embedding ----------
__global__ void k_embed(const int* __restrict__ ids, const float* __restrict__ tok,
                        const float* __restrict__ pos, float* __restrict__ x){
  int t = blockIdx.x;
  int s = t & (S_ - 1);
  int id = ids[t];
  const float* tr = tok + (size_t)id * D_;
  const float* pr = pos + (size_t)s  * D_;
  float* xr = x + (size_t)t * D_;
  for (int d = threadIdx.x; d < D_; d += blockDim.x) xr[d] = tr[d] + pr[d];
}

// ---------- rmsnorm ----------
__global__ __launch_bounds__(256) void k_rmsnorm(const float* __restrict__ x,
                                                 const float* __restrict__ w,
                                                 float* __restrict__ h){
  int t = blockIdx.x;
  const float* xr = x + (size_t)t * D_;
  float* hr = h + (size_t)t * D_;
  float ss = 0.f;
  for (int d = threadIdx.x; d < D_; d += 256){ float v = xr[d]; ss += v * v; }
  ss = wred(ss);
  __shared__ float sp[4];
  __shared__ float sscale;
  if ((threadIdx.x & 63) == 0) sp[threadIdx.x >> 6] = ss;
  __syncthreads();
  if (threadIdx.x == 0){
    float tot = sp[0] + sp[1] + sp[2] + sp[3];
    sscale = rsqrtf(tot / (float)D_ + 1e-6f);
  }
  __syncthreads();
  float sc = sscale;
  for (int d = threadIdx.x; d < D_; d += 256) hr[d] = xr[d] * sc * w[d];
}

// ======================================================================
// MFMA GEMM, fp16x2 split (NPROD=3, fp32-grade) or single f16-hi (NPROD=1).
// LDS layout = fragment-native: [sub16][64 lanes][8 f16], lidx ^= (sub&7).
//   value at (sub, lidx, e) = M[row/col = sub*16 + (lidx&15)][k = (lidx>>4)*8 + e]
// Fragment reads are lane-linear 16B (conflict-free); staging writes are
// permutations of lane-linear (A) / <=2-way (B).
// EPI: 0=bias+store 1=bias+acc 2=bias+gelu+store(MoE hid) 3=moe scaled acc 4=store
// SWZROWS>0: 1D grid, XCD-chunked swizzle, rowTile = lb % SWZROWS.
// ======================================================================
template<int BM, int BN, int NPROD, int EPI, bool MOE, bool APERM, int SWZROWS>
__global__ __launch_bounds__(256) void k_mgemm(
    const float* __restrict__ A, const float* __restrict__ Bm,
    const float* __restrict__ bias, float* __restrict__ C,
    int M, int N, int K,
    const int* __restrict__ seg, const int* __restrict__ perm,
    const float* __restrict__ topw){
  constexpr int FM = BM / 32, FN = BN / 32;
  const int tid = threadIdx.x;
  int rowTile, colTile;
  if (SWZROWS > 0){
    const int nwg = gridDim.x;
    const int bid = blockIdx.x;
    const int lb = (bid & 7) * (nwg >> 3) + (bid >> 3);   // XCD-chunked (nwg%8==0)
    rowTile = lb % SWZROWS;
    colTile = lb / SWZROWS;
  } else {
    colTile = blockIdx.x; rowTile = blockIdx.y;
  }
  int e = 0, s0 = 0, cnt = M;
  if (MOE){ e = blockIdx.z; s0 = seg[e]; cnt = seg[e + 1] - s0; }
  const int row0 = rowTile * BM, col0 = colTile * BN;
  if (MOE && row0 >= cnt) return;
  const float* Bp = Bm + (size_t)e * K * N;
  const float* bp = bias + (size_t)e * N;

  __shared__ __align__(16) _Float16 Ah[BM * 32];
  __shared__ __align__(16) _Float16 Al[NPROD == 3 ? BM * 32 : 8];
  __shared__ __align__(16) _Float16 Bh[BN * 32];
  __shared__ __align__(16) _Float16 Bl[NPROD == 3 ? BN * 32 : 8];

  // A loader
  const int am = (BM == 64) ? (tid >> 2) : (tid >> 1);
  const int agrow = row0 + am;
  const bool aval = agrow < cnt;
  const float* Arow = nullptr;
  if (aval){
    int ridx = APERM ? perm[s0 + agrow] : (MOE ? s0 + agrow : agrow);
    Arow = A + (size_t)ridx * K;
  }
  const int asub = am >> 4;
  // B loader
  const int cb = (BN == 128) ? ((tid & 31) << 2) : ((tid & 15) << 2);
  const int p0 = (BN == 128) ? (tid >> 5) : (tid >> 4);
  constexpr int NBI = (BN == 128) ? 2 : 1;

  const int lane = tid & 63, w = tid >> 6;
  const int wm0 = (w >> 1) * (BM / 2), wn0 = (w & 1) * (BN / 2);

  f32x4_t acc_hh[FM][FN];
  f32x4_t acc_mx[NPROD == 3 ? FM : 1][NPROD == 3 ? FN : 1];
#pragma unroll
  for (int i = 0; i < FM; i++)
#pragma unroll
    for (int j = 0; j < FN; j++){
      acc_hh[i][j] = (f32x4_t){0.f, 0.f, 0.f, 0.f};
      if (NPROD == 3) acc_mx[i][j] = (f32x4_t){0.f, 0.f, 0.f, 0.f};
    }

  for (int k0 = 0; k0 < K; k0 += 32){
    // ---- stage A ----
    if (BM == 64){
      const int kg = tid & 3;
      float4 av0 = make_float4(0,0,0,0), av1 = make_float4(0,0,0,0);
      if (aval){
        av0 = *reinterpret_cast<const float4*>(Arow + k0 + (kg << 3));
        av1 = *reinterpret_cast<const float4*>(Arow + k0 + (kg << 3) + 4);
      }
      const float a8[8] = {av0.x, av0.y, av0.z, av0.w, av1.x, av1.y, av1.z, av1.w};
      half8_t hi, lo;
#pragma unroll
      for (int u = 0; u < 8; u++){
        hi[u] = (_Float16)a8[u];
        if (NPROD == 3) lo[u] = (_Float16)((a8[u] - (float)hi[u]) * 2048.f);
      }
      const int lidx = (am & 15) + (kg << 4);
      const int base = asub * 512 + ((lidx ^ (asub & 7)) << 3);
      *reinterpret_cast<half8_t*>(&Ah[base]) = hi;
      if (NPROD == 3) *reinterpret_cast<half8_t*>(&Al[base]) = lo;
    } else {
      const int kgb = (tid & 1) << 1;
#pragma unroll
      for (int kq = 0; kq < 2; kq++){
        const int kg = kgb + kq;
        float4 av0 = make_float4(0,0,0,0), av1 = make_float4(0,0,0,0);
        if (aval){
          av0 = *reinterpret_cast<const float4*>(Arow + k0 + (kg << 3));
          av1 = *reinterpret_cast<const float4*>(Arow + k0 + (kg << 3) + 4);
        }
        const float a8[8] = {av0.x, av0.y, av0.z, av0.w, av1.x, av1.y, av1.z, av1.w};
        half8_t hi;
#pragma unroll
        for (int u = 0; u < 8; u++) hi[u] = (_Float16)a8[u];
        const int lidx = (am & 15) + (kg << 4);
        *reinterpret_cast<half8_t*>(&Ah[asub * 512 + ((lidx ^ (asub & 7)) << 3)]) = hi;
      }
    }
    // ---- stage B ----
#pragma unroll
    for (int it = 0; it < NBI; it++){
      const int kk = ((BN == 128) ? (p0 + (it << 3)) : p0) << 1;
      const int kg = kk >> 3, e2 = kk & 7;
      const float4 b0 = *reinterpret_cast<const float4*>(Bp + (size_t)(k0 + kk) * N + col0 + cb);
      const float4 b1 = *reinterpret_cast<const float4*>(Bp + (size_t)(k0 + kk + 1) * N + col0 + cb);
      const float b0a[4] = {b0.x, b0.y, b0.z, b0.w};
      const float b1a[4] = {b1.x, b1.y, b1.z, b1.w};
#pragma unroll
      for (int j = 0; j < 4; j++){
        const int c = cb + j, sub = c >> 4;
        const int lidx = (c & 15) + (kg << 4);
        const int base = sub * 512 + ((lidx ^ (sub & 7)) << 3) + e2;
        _Float16 h0 = (_Float16)b0a[j], h1 = (_Float16)b1a[j];
        *reinterpret_cast<half2_t*>(&Bh[base]) = (half2_t){h0, h1};
        if (NPROD == 3){
          _Float16 l0 = (_Float16)((b0a[j] - (float)h0) * 2048.f);
          _Float16 l1 = (_Float16)((b1a[j] - (float)h1) * 2048.f);
          *reinterpret_cast<half2_t*>(&Bl[base]) = (half2_t){l0, l1};
        }
      }
    }
    __syncthreads();
    // ---- fragments + MFMA ----
    half8_t fAh[FM], fBh[FN];
    half8_t fAl[NPROD == 3 ? FM : 1], fBl[NPROD == 3 ? FN : 1];
#pragma unroll
    for (int fm = 0; fm < FM; fm++){
      const int s = (wm0 >> 4) + fm;
      const int ofs = s * 512 + ((lane ^ (s & 7)) << 3);
      fAh[fm] = *reinterpret_cast<const half8_t*>(&Ah[ofs]);
      if (NPROD == 3) fAl[fm] = *reinterpret_cast<const half8_t*>(&Al[ofs]);
    }
#pragma unroll
    for (int fn = 0; fn < FN; fn++){
      const int s = (wn0 >> 4) + fn;
      const int ofs = s * 512 + ((lane ^ (s & 7)) << 3);
      fBh[fn] = *reinterpret_cast<const half8_t*>(&Bh[ofs]);
      if (NPROD == 3) fBl[fn] = *reinterpret_cast<const half8_t*>(&Bl[ofs]);
    }
#pragma unroll
    for (int fm = 0; fm < FM; fm++)
#pragma unroll
      for (int fn = 0; fn < FN; fn++){
        acc_hh[fm][fn] = __builtin_amdgcn_mfma_f32_16x16x32_f16(
            fAh[fm], fBh[fn], acc_hh[fm][fn], 0, 0, 0);
        if (NPROD == 3){
          acc_mx[fm][fn] = __builtin_amdgcn_mfma_f32_16x16x32_f16(
              fAh[fm], fBl[fn], acc_mx[fm][fn], 0, 0, 0);
          acc_mx[fm][fn] = __builtin_amdgcn_mfma_f32_16x16x32_f16(
              fAl[fm], fBh[fn], acc_mx[fm][fn], 0, 0, 0);
        }
      }
    __syncthreads();
  }

  // ---- epilogue ----
  const int lr = lane & 15, kg4 = lane >> 4;
#pragma unroll
  for (int fm = 0; fm < FM; fm++){
#pragma unroll
    for (int reg = 0; reg < 4; reg++){
      const int grow = row0 + wm0 + fm * 16 + (kg4 << 2) + reg;
      if (grow >= cnt) continue;
      int trow = 0; float tw = 0.f;
      if (EPI == 3){ trow = perm[s0 + grow]; tw = topw[trow]; }
#pragma unroll
      for (int fn = 0; fn < FN; fn++){
        const int col = col0 + wn0 + fn * 16 + lr;
        float v = acc_hh[fm][fn][reg];
        if (NPROD == 3) v += acc_mx[fm][fn][reg] * (1.f / 2048.f);
        if (EPI == 0){
          C[(size_t)grow * N + col] = v + bp[col];
        } else if (EPI == 1){
          C[(size_t)grow * N + col] += v + bp[col];
        } else if (EPI == 2){
          C[(size_t)(s0 + grow) * N + col] = gelu_f(v + bp[col]);
        } else if (EPI == 3){
          C[(size_t)trow * N + col] += tw * (v + bp[col]);
        } else {
          C[(size_t)grow * N + col] = v;
        }
      }
    }
  }
}

// ---------- causal attention v3 (unchanged, known-good) ----------
__global__ __launch_bounds__(256) void k_attn3(const float* __restrict__ qkv,
                                               float* __restrict__ o){
  __shared__ float Ks[64 * 64];
  __shared__ float Vt[64 * 64];
  __shared__ float qs[8][64];
  __shared__ float ps[4][2][64];
  const int tid = threadIdx.x;
  const int w = tid >> 6, lane = tid & 63;
  const int bid = blockIdx.x;
  const int bh = bid & 15;
  const int qb = (int)(__brev((unsigned)(bid >> 4)) >> 25);
  const int h = bh & 7, b = bh >> 3;
  const int qbase = qb << 3;
  const int qr0 = qbase + (w << 1), qr1 = qr0 + 1;
  const size_t bbase = (size_t)(b << 10) * D3_;
  const int hoff = h * 64;
  {
    const int r0 = tid >> 6, d0 = tid & 63;
    qs[r0][d0] = qkv[bbase + (size_t)(qbase + r0) * D3_ + hoff + d0] * 0.125f;
    const int r1 = (tid + 256) >> 6, d1 = tid & 63;
    qs[r1][d1] = qkv[bbase + (size_t)(qbase + r1) * D3_ + hoff + d1] * 0.125f;
  }
  float m0 = -1e30f, m1 = -1e30f;
  float l0 = 0.f, l1 = 0.f;
  float a0p0 = 0.f, a0p1 = 0.f, a0p2 = 0.f, a0p3 = 0.f;
  float a1p0 = 0.f, a1p1 = 0.f, a1p2 = 0.f, a1p3 = 0.f;
  const int nt = ((qbase + 7) >> 6) + 1;
  const int jr = tid >> 2, cg = tid & 3;
  for (int jt = 0; jt < nt; jt++){
    const int j0 = jt << 6;
    __syncthreads();
    const float* krow = qkv + bbase + (size_t)(j0 + jr) * D3_ + 512 + hoff;
#pragma unroll
    for (int cc = 0; cc < 4; cc++){
      const int c = cg + (cc << 2);
      const float4 kv4 = *reinterpret_cast<const float4*>(krow + (c << 2));
      *reinterpret_cast<float4*>(&Ks[(jr << 6) + ((c ^ (jr & 7)) << 2)]) = kv4;
      const float4 vv4 = *reinterpret_cast<const float4*>(krow + 512 + (c << 2));
      const int d0 = c << 2, jh = jr >> 2, jl = jr & 3;
      Vt[((d0 + 0) << 6) + ((jh ^ ((d0 + 0) & 7)) << 2) + jl] = vv4.x;
      Vt[((d0 + 1) << 6) + ((jh ^ ((d0 + 1) & 7)) << 2) + jl] = vv4.y;
      Vt[((d0 + 2) << 6) + ((jh ^ ((d0 + 2) & 7)) << 2) + jl] = vv4.z;
      Vt[((d0 + 3) << 6) + ((jh ^ ((d0 + 3) & 7)) << 2) + jl] = vv4.w;
    }
    __syncthreads();
    float s0p0 = 0.f, s0p1 = 0.f, s0p2 = 0.f, s0p3 = 0.f;
    float s1p0 = 0.f, s1p1 = 0.f, s1p2 = 0.f, s1p3 = 0.f;
#pragma unroll
    for (int c = 0; c < 16; c++){
      const float4 kx = *reinterpret_cast<const float4*>(
          &Ks[(lane << 6) + ((c ^ (lane & 7)) << 2)]);
      const float4 q0c = *reinterpret_cast<const float4*>(&qs[w << 1][c << 2]);
      const float4 q1c = *reinterpret_cast<const float4*>(&qs[(w << 1) + 1][c << 2]);
      s0p0 = fmaf(q0c.x, kx.x, s0p0); s0p1 = fmaf(q0c.y, kx.y, s0p1);
      s0p2 = fmaf(q0c.z, kx.z, s0p2); s0p3 = fmaf(q0c.w, kx.w, s0p3);
      s1p0 = fmaf(q1c.x, kx.x, s1p0); s1p1 = fmaf(q1c.y, kx.y, s1p1);
      s1p2 = fmaf(q1c.z, kx.z, s1p2); s1p3 = fmaf(q1c.w, kx.w, s1p3);
    }
    const float s0 = (s0p0 + s0p1) + (s0p2 + s0p3);
    const float s1 = (s1p0 + s1p1) + (s1p2 + s1p3);
    const int jg = j0 + lane;
    const float s0m = (jg <= qr0) ? s0 : -1e30f;
    const float s1m = (jg <= qr1) ? s1 : -1e30f;
    const float mn0 = fmaxf(m0, wredmax(s0m));
    const float mn1 = fmaxf(m1, wredmax(s1m));
    const float p0 = __expf(s0m - mn0);
    const float p1 = __expf(s1m - mn1);
    const float cr0 = __expf(m0 - mn0);
    const float cr1 = __expf(m1 - mn1);
    l0 = l0 * cr0 + p0;
    l1 = l1 * cr1 + p1;
    a0p0 *= cr0; a0p1 *= cr0; a0p2 *= cr0; a0p3 *= cr0;
    a1p0 *= cr1; a1p1 *= cr1; a1p2 *= cr1; a1p3 *= cr1;
    m0 = mn0; m1 = mn1;
    ps[w][0][lane] = p0;
    ps[w][1][lane] = p1;
#pragma unroll
    for (int c = 0; c < 16; c++){
      const float4 vx = *reinterpret_cast<const float4*>(
          &Vt[(lane << 6) + ((c ^ (lane & 7)) << 2)]);
      const float4 p0v = *reinterpret_cast<const float4*>(&ps[w][0][c << 2]);
      const float4 p1v = *reinterpret_cast<const float4*>(&ps[w][1][c << 2]);
      a0p0 = fmaf(p0v.x, vx.x, a0p0); a0p1 = fmaf(p0v.y, vx.y, a0p1);
      a0p2 = fmaf(p0v.z, vx.z, a0p2); a0p3 = fmaf(p0v.w, vx.w, a0p3);
      a1p0 = fmaf(p1v.x, vx.x, a1p0); a1p1 = fmaf(p1v.y, vx.y, a1p1);
      a1p2 = fmaf(p1v.z, vx.z, a1p2); a1p3 = fmaf(p1v.w, vx.w, a1p3);
    }
  }
  const float l0t = wred(l0);
  const float l1t = wred(l1);
  const int t0 = (b << 10) + qr0;
  o[(size_t)t0 * D_ + hoff + lane]       = ((a0p0 + a0p1) + (a0p2 + a0p3)) / l0t;
  o[(size_t)(t0 + 1) * D_ + hoff + lane] = ((a1p0 + a1p1) + (a1p2 + a1p3)) / l1t;
}

// ---------- router (no global atomics) ----------
__global__ __launch_bounds__(64) void k_router(const float* __restrict__ h2,
                                               const float* __restrict__ rW,
                                               const float* __restrict__ rb,
                                               float* __restrict__ rl_out,
                                               float* __restrict__ topw,
                                               int* __restrict__ topi){
  int t = blockIdx.x, lane = threadIdx.x;
  const float* hr = h2 + (size_t)t * D_;
  float acc[8] = {0,0,0,0,0,0,0,0};
  for (int d = lane; d < D_; d += 64){
    float hv = hr[d];
    const float* wr = rW + (size_t)d * E_;
    float4 w0 = *reinterpret_cast<const float4*>(wr);
    float4 w1 = *reinterpret_cast<const float4*>(wr + 4);
    acc[0] += hv * w0.x; acc[1] += hv * w0.y; acc[2] += hv * w0.z; acc[3] += hv * w0.w;
    acc[4] += hv * w1.x; acc[5] += hv * w1.y; acc[6] += hv * w1.z; acc[7] += hv * w1.w;
  }
  float rl[8];
#pragma unroll
  for (int e = 0; e < 8; e++) rl[e] = wred(acc[e]) + rb[e];
  float mx = rl[0];
#pragma unroll
  for (int e = 1; e < 8; e++) mx = fmaxf(mx, rl[e]);
  float p[8], s = 0.f;
#pragma unroll
  for (int e = 0; e < 8; e++){ p[e] = __expf(rl[e] - mx); s += p[e]; }
  float inv = 1.f / s;
  int arg = 0; float best = rl[0];
#pragma unroll
  for (int e = 1; e < 8; e++) if (rl[e] > best){ best = rl[e]; arg = e; }
  if (lane == 0){
#pragma unroll
    for (int e = 0; e < 8; e++) rl_out[(size_t)t * E_ + e] = rl[e];
    topw[t] = p[arg] * inv;
    topi[t] = arg;
  }
}

// ---------- single-wave routing scan: seg/perm/aux ----------
__global__ __launch_bounds__(64) void k_route_scan(const int* __restrict__ topi,
                                                   const float* __restrict__ rl,
                                                   int* __restrict__ seg,
                                                   int* __restrict__ perm,
                                                   float* __restrict__ aux){
  const int lane = threadIdx.x;
  int c[8] = {0,0,0,0,0,0,0,0};
  for (int i = 0; i < 32; i++) c[topi[lane * 32 + i]]++;
  int base[8], tot[8];
#pragma unroll
  for (int e = 0; e < 8; e++){
    int inc = c[e];
#pragma unroll
    for (int off = 1; off < 64; off <<= 1){
      int n = __shfl_up(inc, off);
      if (lane >= off) inc += n;
    }
    base[e] = inc - c[e];
    tot[e] = __shfl(inc, 63);
  }
  int segv[9]; segv[0] = 0;
#pragma unroll
  for (int e = 0; e < 8; e++) segv[e + 1] = segv[e] + tot[e];
  if (lane < 9) seg[lane] = segv[lane];
  int cur[8];
#pragma unroll
  for (int e = 0; e < 8; e++) cur[e] = segv[e] + base[e];
  for (int i = 0; i < 32; i++){
    int t = lane * 32 + i;
    int e = topi[t];
    perm[cur[e]++] = t;
  }
  float ps[8] = {0,0,0,0,0,0,0,0};
  for (int i = 0; i < 32; i++){
    const float* r = rl + (size_t)(lane * 32 + i) * E_;
    float v[8], mx = r[0];
#pragma unroll
    for (int e = 0; e < 8; e++) v[e] = r[e];
#pragma unroll
    for (int e = 1; e < 8; e++) mx = fmaxf(mx, v[e]);
    float s = 0.f;
#pragma unroll
    for (int e = 0; e < 8; e++){ v[e] = __expf(v[e] - mx); s += v[e]; }
    float is = 1.f / s;
#pragma unroll
    for (int e = 0; e < 8; e++) ps[e] += v[e] * is;
  }
  float av = 0.f;
#pragma unroll
  for (int e = 0; e < 8; e++){
    float pst = wred(ps[e]);
    av += (float)tot[e] * pst;
  }
  if (lane == 0) aux[0] += 8.f * av / ((float)T_ * (float)T_);
}

// ======================= host launcher =======================
extern "C" void kernel_launch(void* const* d_in, const int* in_sizes, int n_in,
                              void* d_out, int out_size, void* d_ws, size_t ws_size,
                              hipStream_t stream){
  const int*   ids  = (const int*)  d_in[0];
  const float* tok  = (const float*)d_in[1];
  const float* pos  = (const float*)d_in[2];
  const float* Wqkv = (const float*)d_in[3];
  const float* bqkv = (const float*)d_in[4];
  const float* Wo   = (const float*)d_in[5];
  const float* bo   = (const float*)d_in[6];
  const float* rW   = (const float*)d_in[7];
  const float* rb   = (const float*)d_in[8];
  const float* eW1  = (const float*)d_in[9];
  const float* eb1  = (const float*)d_in[10];
  const float* eW2  = (const float*)d_in[11];
  const float* eb2  = (const float*)d_in[12];
  const float* n1w  = (const float*)d_in[13];
  const float* n2w  = (const float*)d_in[14];
  const float* noww = (const float*)d_in[15];
  const float* lmW  = (const float*)d_in[16];

  float* out    = (float*)d_out;
  float* logits = out;                             // [T,V]
  float* aux    = out + (size_t)T_ * V_;           // [1]
  float* rlog   = aux + 1;                         // [L,T,E]

  float* ws = (float*)d_ws;
  size_t off = 0;
  float* x     = ws + off; off += (size_t)T_ * D_;
  float* h     = ws + off; off += (size_t)T_ * D_;
  float* qkv   = ws + off; off += (size_t)T_ * D3_;
  float* attno = ws + off; off += (size_t)T_ * D_;
  float* hid   = ws + off; off += (size_t)T_ * FF_;
  float* topw  = ws + off; off += T_;
  int* topi    = (int*)(ws + off); off += T_;
  int* perm    = (int*)(ws + off); off += T_;
  int* seg     = (int*)(ws + off); off += (E_ + 1);

  hipMemsetAsync(aux, 0, sizeof(float), stream);
  k_embed<<<T_, 256, 0, stream>>>(ids, tok, pos, x);

  for (int l = 0; l < L_; l++){
    // --- attention block ---
    k_rmsnorm<<<T_, 256, 0, stream>>>(x, n1w + (size_t)l * D_, h);
    k_mgemm<64, 128, 3, 0, false, false, 0><<<dim3(D3_ / 128, T_ / 64), 256, 0, stream>>>(
        h, Wqkv + (size_t)l * D_ * D3_, bqkv + (size_t)l * D3_, qkv,
        T_, D3_, D_, seg, perm, topw);
    k_attn3<<<B_ * H_ * (S_ / 8), 256, 0, stream>>>(qkv, attno);
    k_mgemm<64, 64, 3, 1, false, false, 0><<<dim3(D_ / 64, T_ / 64), 256, 0, stream>>>(
        attno, Wo + (size_t)l * D_ * D_, bo + (size_t)l * D_, x,
        T_, D_, D_, seg, perm, topw);
    // --- MoE block ---
    k_rmsnorm<<<T_, 256, 0, stream>>>(x, n2w + (size_t)l * D_, h);
    k_router<<<T_, 64, 0, stream>>>(h, rW + (size_t)l * D_ * E_, rb + (size_t)l * E_,
                                    rlog + (size_t)l * T_ * E_, topw, topi);
    k_route_scan<<<1, 64, 0, stream>>>(topi, rlog + (size_t)l * T_ * E_, seg, perm, aux);
    k_mgemm<64, 128, 3, 2, true, true, 0><<<dim3(FF_ / 128, T_ / 64, E_), 256, 0, stream>>>(
        h, eW1 + (size_t)l * E_ * D_ * FF_, eb1 + (size_t)l * E_ * FF_, hid,
        T_, FF_, D_, seg, perm, topw);
    k_mgemm<64, 64, 3, 3, true, false, 0><<<dim3(D_ / 64, T_ / 64, E_), 256, 0, stream>>>(
        hid, eW2 + (size_t)l * E_ * FF_ * D_, eb2 + (size_t)l * E_ * D_, x,
        T_, D_, FF_, seg, perm, topw);
  }

  // --- final norm + LM head (f16-hi, XCD-chunked 1D grid: 16 rowTiles) ---
  k_rmsnorm<<<T_, 256, 0, stream>>>(x, noww, h);
  k_mgemm<128, 128, 1, 4, false, false, 16><<<(T_ / 128) * (V_ / 128), 256, 0, stream>>>(
      h, lmW, noww /*unused*/, logits, T_, V_, D_, seg, perm, topw);
}

// Round 6
// 4651.921 us; speedup vs baseline: 4.2443x; 1.0295x over previous
//
#include <hip/hip_runtime.h>

// ==== model dims (fixed by the reference) ====
constexpr int B_  = 2, S_ = 1024, T_ = 2048;   // T = B*S tokens
constexpr int D_  = 512, H_ = 8, DH_ = 64;
constexpr int L_  = 12, E_ = 8, FF_ = 2048;
constexpr int V_  = 32000, D3_ = 1536;

using half8_t = __attribute__((ext_vector_type(8))) _Float16;
using half2_t = __attribute__((ext_vector_type(2))) _Float16;
using f32x4_t = __attribute__((ext_vector_type(4))) float;

// ---------- helpers ----------
__device__ __forceinline__ float wred(float v){
#pragma unroll
  for (int off = 32; off; off >>= 1) v += __shfl_xor(v, off);
  return v;
}
__device__ __forceinline__ float wredmax(float v){
#pragma unroll
  for (int off = 32; off; off >>= 1) v = fmaxf(v, __shfl_xor(v, off));
  return v;
}
__device__ __forceinline__ float gelu_f(float v){
  return 0.5f * v * (1.f + erff(v * 0.70710678118654752f));
}

// ---------- embedding ----------
__global__ void k_embed(const int* __restrict__ ids, const float* __restrict__ tok,
                        const float* __restrict__ pos, float* __restrict__ x){
  int t = blockIdx.x;
  int s = t & (S_ - 1);
  int id = ids[t];
  const float* tr = tok + (size_t)id * D_;
  const float* pr = pos + (size_t)s  * D_;
  float* xr = x + (size_t)t * D_;
  for (int d = threadIdx.x; d < D_; d += blockDim.x) xr[d] = tr[d] + pr[d];
}

// ---------- rmsnorm (norm1 + final norm) ----------
__global__ __launch_bounds__(256) void k_rmsnorm(const float* __restrict__ x,
                                                 const float* __restrict__ w,
                                                 float* __restrict__ h){
  int t = blockIdx.x;
  const float* xr = x + (size_t)t * D_;
  float* hr = h + (size_t)t * D_;
  float ss = 0.f;
  for (int d = threadIdx.x; d < D_; d += 256){ float v = xr[d]; ss += v * v; }
  ss = wred(ss);
  __shared__ float sp[4];
  __shared__ float sscale;
  if ((threadIdx.x & 63) == 0) sp[threadIdx.x >> 6] = ss;
  __syncthreads();
  if (threadIdx.x == 0){
    float tot = sp[0] + sp[1] + sp[2] + sp[3];
    sscale = rsqrtf(tot / (float)D_ + 1e-6f);
  }
  __syncthreads();
  float sc = sscale;
  for (int d = threadIdx.x; d < D_; d += 256) hr[d] = xr[d] * sc * w[d];
}

// ---------- fused rmsnorm#2 + router: one wave per token ----------
__global__ __launch_bounds__(64) void k_norm_router(
    const float* __restrict__ x, const float* __restrict__ nw,
    const float* __restrict__ rW, const float* __restrict__ rb,
    float* __restrict__ h, float* __restrict__ rl_out,
    float* __restrict__ topw, int* __restrict__ topi){
  const int t = blockIdx.x, lane = threadIdx.x;
  const float* xr = x + (size_t)t * D_;
  const float4 xv0 = *reinterpret_cast<const float4*>(xr + (lane << 2));
  const float4 xv1 = *reinterpret_cast<const float4*>(xr + 256 + (lane << 2));
  float ss = xv0.x*xv0.x + xv0.y*xv0.y + xv0.z*xv0.z + xv0.w*xv0.w
           + xv1.x*xv1.x + xv1.y*xv1.y + xv1.z*xv1.z + xv1.w*xv1.w;
  ss = wred(ss);
  const float sc = rsqrtf(ss * (1.f / (float)D_) + 1e-6f);
  const float4 w0 = *reinterpret_cast<const float4*>(nw + (lane << 2));
  const float4 w1 = *reinterpret_cast<const float4*>(nw + 256 + (lane << 2));
  float hv[8];
  hv[0] = xv0.x*sc*w0.x; hv[1] = xv0.y*sc*w0.y; hv[2] = xv0.z*sc*w0.z; hv[3] = xv0.w*sc*w0.w;
  hv[4] = xv1.x*sc*w1.x; hv[5] = xv1.y*sc*w1.y; hv[6] = xv1.z*sc*w1.z; hv[7] = xv1.w*sc*w1.w;
  float* hr = h + (size_t)t * D_;
  *reinterpret_cast<float4*>(hr + (lane << 2))       = make_float4(hv[0], hv[1], hv[2], hv[3]);
  *reinterpret_cast<float4*>(hr + 256 + (lane << 2)) = make_float4(hv[4], hv[5], hv[6], hv[7]);
  float acc[8] = {0,0,0,0,0,0,0,0};
#pragma unroll
  for (int u = 0; u < 8; u++){
    const int d = (u < 4) ? ((lane << 2) + u) : (256 + (lane << 2) + u - 4);
    const float4 ra = *reinterpret_cast<const float4*>(rW + (size_t)d * E_);
    const float4 rb4 = *reinterpret_cast<const float4*>(rW + (size_t)d * E_ + 4);
    acc[0] += hv[u]*ra.x;  acc[1] += hv[u]*ra.y;  acc[2] += hv[u]*ra.z;  acc[3] += hv[u]*ra.w;
    acc[4] += hv[u]*rb4.x; acc[5] += hv[u]*rb4.y; acc[6] += hv[u]*rb4.z; acc[7] += hv[u]*rb4.w;
  }
  float rl[8];
#pragma unroll
  for (int e = 0; e < 8; e++) rl[e] = wred(acc[e]) + rb[e];
  float mx = rl[0];
#pragma unroll
  for (int e = 1; e < 8; e++) mx = fmaxf(mx, rl[e]);
  float p[8], s = 0.f;
#pragma unroll
  for (int e = 0; e < 8; e++){ p[e] = __expf(rl[e] - mx); s += p[e]; }
  const float inv = 1.f / s;
  int arg = 0; float best = rl[0];
#pragma unroll
  for (int e = 1; e < 8; e++) if (rl[e] > best){ best = rl[e]; arg = e; }
  if (lane == 0){
#pragma unroll
    for (int e = 0; e < 8; e++) rl_out[(size_t)t * E_ + e] = rl[e];
    topw[t] = p[arg] * inv;
    topi[t] = arg;
  }
}

// ---------- parallel routing scan: one 1024-thread block ----------
__global__ __launch_bounds__(1024) void k_route_scan2(
    const int* __restrict__ topi, const float* __restrict__ rl,
    int* __restrict__ seg, int* __restrict__ perm, float* __restrict__ aux){
  __shared__ int cnt[8], segs[9], cur[8];
  __shared__ float psums[8];
  const int tid = threadIdx.x;
  if (tid < 8){ cnt[tid] = 0; psums[tid] = 0.f; }
  __syncthreads();
  const int t0 = tid, t1 = tid + 1024;
  const int e0 = topi[t0], e1 = topi[t1];
  atomicAdd(&cnt[e0], 1);
  atomicAdd(&cnt[e1], 1);
  float ps[8] = {0,0,0,0,0,0,0,0};
#pragma unroll
  for (int k = 0; k < 2; k++){
    const float* r = rl + (size_t)(k ? t1 : t0) * E_;
    float v[8];
#pragma unroll
    for (int e = 0; e < 8; e++) v[e] = r[e];
    float mx = v[0];
#pragma unroll
    for (int e = 1; e < 8; e++) mx = fmaxf(mx, v[e]);
    float s = 0.f;
#pragma unroll
    for (int e = 0; e < 8; e++){ v[e] = __expf(v[e] - mx); s += v[e]; }
    const float is = 1.f / s;
#pragma unroll
    for (int e = 0; e < 8; e++) ps[e] += v[e] * is;
  }
#pragma unroll
  for (int e = 0; e < 8; e++) ps[e] = wred(ps[e]);
  if ((tid & 63) == 0){
#pragma unroll
    for (int e = 0; e < 8; e++) atomicAdd(&psums[e], ps[e]);
  }
  __syncthreads();
  if (tid == 0){
    segs[0] = 0;
#pragma unroll
    for (int e = 0; e < 8; e++) segs[e + 1] = segs[e] + cnt[e];
#pragma unroll
    for (int e = 0; e < 8; e++) cur[e] = segs[e];
  }
  __syncthreads();
  if (tid < 9) seg[tid] = segs[tid];
  const int p0 = atomicAdd(&cur[e0], 1); perm[p0] = t0;
  const int p1 = atomicAdd(&cur[e1], 1); perm[p1] = t1;
  if (tid == 0){
    float av = 0.f;
#pragma unroll
    for (int e = 0; e < 8; e++) av += (float)cnt[e] * psums[e];
    aux[0] += 8.f * av * (1.f / ((float)T_ * (float)T_));
  }
}

// ======================================================================
// MFMA GEMM, fp16x2 split (NPROD=3, fp32-grade) or single f16-hi (NPROD=1).
// LDS layout = fragment-native: [sub16][64 lanes][8 f16], lidx ^= (sub&7).
// EPI: 0=bias+store 1=bias+acc 2=bias+gelu+store(MoE hid) 3=moe scaled acc 4=store
// SWZROWS>0: 1D grid, XCD-chunked swizzle, rowTile = lb % SWZROWS.
// ======================================================================
template<int BM, int BN, int NPROD, int EPI, bool MOE, bool APERM, int SWZROWS>
__global__ __launch_bounds__(256) void k_mgemm(
    const float* __restrict__ A, const float* __restrict__ Bm,
    const float* __restrict__ bias, float* __restrict__ C,
    int M, int N, int K,
    const int* __restrict__ seg, const int* __restrict__ perm,
    const float* __restrict__ topw){
  constexpr int FM = BM / 32, FN = BN / 32;
  const int tid = threadIdx.x;
  int rowTile, colTile;
  if (SWZROWS > 0){
    const int nwg = gridDim.x;
    const int bid = blockIdx.x;
    const int lb = (bid & 7) * (nwg >> 3) + (bid >> 3);   // XCD-chunked (nwg%8==0)
    rowTile = lb % SWZROWS;
    colTile = lb / SWZROWS;
  } else {
    colTile = blockIdx.x; rowTile = blockIdx.y;
  }
  int e = 0, s0 = 0, cnt = M;
  if (MOE){ e = blockIdx.z; s0 = seg[e]; cnt = seg[e + 1] - s0; }
  const int row0 = rowTile * BM, col0 = colTile * BN;
  if (MOE && row0 >= cnt) return;
  const float* Bp = Bm + (size_t)e * K * N;
  const float* bp = bias + (size_t)e * N;

  __shared__ __align__(16) _Float16 Ah[BM * 32];
  __shared__ __align__(16) _Float16 Al[NPROD == 3 ? BM * 32 : 8];
  __shared__ __align__(16) _Float16 Bh[BN * 32];
  __shared__ __align__(16) _Float16 Bl[NPROD == 3 ? BN * 32 : 8];

  // A loader
  const int am = (BM == 64) ? (tid >> 2) : (tid >> 1);
  const int agrow = row0 + am;
  const bool aval = agrow < cnt;
  const float* Arow = nullptr;
  if (aval){
    int ridx = APERM ? perm[s0 + agrow] : (MOE ? s0 + agrow : agrow);
    Arow = A + (size_t)ridx * K;
  }
  const int asub = am >> 4;
  // B loader
  const int cb = (BN == 128) ? ((tid & 31) << 2) : ((tid & 15) << 2);
  const int p0 = (BN == 128) ? (tid >> 5) : (tid >> 4);
  constexpr int NBI = (BN == 128) ? 2 : 1;

  const int lane = tid & 63, w = tid >> 6;
  const int wm0 = (w >> 1) * (BM / 2), wn0 = (w & 1) * (BN / 2);

  f32x4_t acc_hh[FM][FN];
  f32x4_t acc_mx[NPROD == 3 ? FM : 1][NPROD == 3 ? FN : 1];
#pragma unroll
  for (int i = 0; i < FM; i++)
#pragma unroll
    for (int j = 0; j < FN; j++){
      acc_hh[i][j] = (f32x4_t){0.f, 0.f, 0.f, 0.f};
      if (NPROD == 3) acc_mx[i][j] = (f32x4_t){0.f, 0.f, 0.f, 0.f};
    }

  for (int k0 = 0; k0 < K; k0 += 32){
    // ---- stage A ----
    if (BM == 64){
      const int kg = tid & 3;
      float4 av0 = make_float4(0,0,0,0), av1 = make_float4(0,0,0,0);
      if (aval){
        av0 = *reinterpret_cast<const float4*>(Arow + k0 + (kg << 3));
        av1 = *reinterpret_cast<const float4*>(Arow + k0 + (kg << 3) + 4);
      }
      const float a8[8] = {av0.x, av0.y, av0.z, av0.w, av1.x, av1.y, av1.z, av1.w};
      half8_t hi, lo;
#pragma unroll
      for (int u = 0; u < 8; u++){
        hi[u] = (_Float16)a8[u];
        if (NPROD == 3) lo[u] = (_Float16)((a8[u] - (float)hi[u]) * 2048.f);
      }
      const int lidx = (am & 15) + (kg << 4);
      const int base = asub * 512 + ((lidx ^ (asub & 7)) << 3);
      *reinterpret_cast<half8_t*>(&Ah[base]) = hi;
      if (NPROD == 3) *reinterpret_cast<half8_t*>(&Al[base]) = lo;
    } else {
      const int kgb = (tid & 1) << 1;
#pragma unroll
      for (int kq = 0; kq < 2; kq++){
        const int kg = kgb + kq;
        float4 av0 = make_float4(0,0,0,0), av1 = make_float4(0,0,0,0);
        if (aval){
          av0 = *reinterpret_cast<const float4*>(Arow + k0 + (kg << 3));
          av1 = *reinterpret_cast<const float4*>(Arow + k0 + (kg << 3) + 4);
        }
        const float a8[8] = {av0.x, av0.y, av0.z, av0.w, av1.x, av1.y, av1.z, av1.w};
        half8_t hi;
#pragma unroll
        for (int u = 0; u < 8; u++) hi[u] = (_Float16)a8[u];
        const int lidx = (am & 15) + (kg << 4);
        *reinterpret_cast<half8_t*>(&Ah[asub * 512 + ((lidx ^ (asub & 7)) << 3)]) = hi;
      }
    }
    // ---- stage B ----
#pragma unroll
    for (int it = 0; it < NBI; it++){
      const int kk = ((BN == 128) ? (p0 + (it << 3)) : p0) << 1;
      const int kg = kk >> 3, e2 = kk & 7;
      const float4 b0 = *reinterpret_cast<const float4*>(Bp + (size_t)(k0 + kk) * N + col0 + cb);
      const float4 b1 = *reinterpret_cast<const float4*>(Bp + (size_t)(k0 + kk + 1) * N + col0 + cb);
      const float b0a[4] = {b0.x, b0.y, b0.z, b0.w};
      const float b1a[4] = {b1.x, b1.y, b1.z, b1.w};
#pragma unroll
      for (int j = 0; j < 4; j++){
        const int c = cb + j, sub = c >> 4;
        const int lidx = (c & 15) + (kg << 4);
        const int base = sub * 512 + ((lidx ^ (sub & 7)) << 3) + e2;
        _Float16 h0 = (_Float16)b0a[j], h1 = (_Float16)b1a[j];
        *reinterpret_cast<half2_t*>(&Bh[base]) = (half2_t){h0, h1};
        if (NPROD == 3){
          _Float16 l0 = (_Float16)((b0a[j] - (float)h0) * 2048.f);
          _Float16 l1 = (_Float16)((b1a[j] - (float)h1) * 2048.f);
          *reinterpret_cast<half2_t*>(&Bl[base]) = (half2_t){l0, l1};
        }
      }
    }
    __syncthreads();
    // ---- fragments + MFMA ----
    half8_t fAh[FM], fBh[FN];
    half8_t fAl[NPROD == 3 ? FM : 1], fBl[NPROD == 3 ? FN : 1];
#pragma unroll
    for (int fm = 0; fm < FM; fm++){
      const int s = (wm0 >> 4) + fm;
      const int ofs = s * 512 + ((lane ^ (s & 7)) << 3);
      fAh[fm] = *reinterpret_cast<const half8_t*>(&Ah[ofs]);
      if (NPROD == 3) fAl[fm] = *reinterpret_cast<const half8_t*>(&Al[ofs]);
    }
#pragma unroll
    for (int fn = 0; fn < FN; fn++){
      const int s = (wn0 >> 4) + fn;
      const int ofs = s * 512 + ((lane ^ (s & 7)) << 3);
      fBh[fn] = *reinterpret_cast<const half8_t*>(&Bh[ofs]);
      if (NPROD == 3) fBl[fn] = *reinterpret_cast<const half8_t*>(&Bl[ofs]);
    }
#pragma unroll
    for (int fm = 0; fm < FM; fm++)
#pragma unroll
      for (int fn = 0; fn < FN; fn++){
        acc_hh[fm][fn] = __builtin_amdgcn_mfma_f32_16x16x32_f16(
            fAh[fm], fBh[fn], acc_hh[fm][fn], 0, 0, 0);
        if (NPROD == 3){
          acc_mx[fm][fn] = __builtin_amdgcn_mfma_f32_16x16x32_f16(
              fAh[fm], fBl[fn], acc_mx[fm][fn], 0, 0, 0);
          acc_mx[fm][fn] = __builtin_amdgcn_mfma_f32_16x16x32_f16(
              fAl[fm], fBh[fn], acc_mx[fm][fn], 0, 0, 0);
        }
      }
    __syncthreads();
  }

  // ---- epilogue ----
  const int lr = lane & 15, kg4 = lane >> 4;
#pragma unroll
  for (int fm = 0; fm < FM; fm++){
#pragma unroll
    for (int reg = 0; reg < 4; reg++){
      const int grow = row0 + wm0 + fm * 16 + (kg4 << 2) + reg;
      if (grow >= cnt) continue;
      int trow = 0; float tw = 0.f;
      if (EPI == 3){ trow = perm[s0 + grow]; tw = topw[trow]; }
#pragma unroll
      for (int fn = 0; fn < FN; fn++){
        const int col = col0 + wn0 + fn * 16 + lr;
        float v = acc_hh[fm][fn][reg];
        if (NPROD == 3) v += acc_mx[fm][fn][reg] * (1.f / 2048.f);
        if (EPI == 0){
          C[(size_t)grow * N + col] = v + bp[col];
        } else if (EPI == 1){
          C[(size_t)grow * N + col] += v + bp[col];
        } else if (EPI == 2){
          C[(size_t)(s0 + grow) * N + col] = gelu_f(v + bp[col]);
        } else if (EPI == 3){
          C[(size_t)trow * N + col] += tw * (v + bp[col]);
        } else {
          C[(size_t)grow * N + col] = v;
        }
      }
    }
  }
}

// ---------- causal attention v3 (unchanged, known-good) ----------
__global__ __launch_bounds__(256) void k_attn3(const float* __restrict__ qkv,
                                               float* __restrict__ o){
  __shared__ float Ks[64 * 64];
  __shared__ float Vt[64 * 64];
  __shared__ float qs[8][64];
  __shared__ float ps[4][2][64];
  const int tid = threadIdx.x;
  const int w = tid >> 6, lane = tid & 63;
  const int bid = blockIdx.x;
  const int bh = bid & 15;
  const int qb = (int)(__brev((unsigned)(bid >> 4)) >> 25);
  const int h = bh & 7, b = bh >> 3;
  const int qbase = qb << 3;
  const int qr0 = qbase + (w << 1), qr1 = qr0 + 1;
  const size_t bbase = (size_t)(b << 10) * D3_;
  const int hoff = h * 64;
  {
    const int r0 = tid >> 6, d0 = tid & 63;
    qs[r0][d0] = qkv[bbase + (size_t)(qbase + r0) * D3_ + hoff + d0] * 0.125f;
    const int r1 = (tid + 256) >> 6, d1 = tid & 63;
    qs[r1][d1] = qkv[bbase + (size_t)(qbase + r1) * D3_ + hoff + d1] * 0.125f;
  }
  float m0 = -1e30f, m1 = -1e30f;
  float l0 = 0.f, l1 = 0.f;
  float a0p0 = 0.f, a0p1 = 0.f, a0p2 = 0.f, a0p3 = 0.f;
  float a1p0 = 0.f, a1p1 = 0.f, a1p2 = 0.f, a1p3 = 0.f;
  const int nt = ((qbase + 7) >> 6) + 1;
  const int jr = tid >> 2, cg = tid & 3;
  for (int jt = 0; jt < nt; jt++){
    const int j0 = jt << 6;
    __syncthreads();
    const float* krow = qkv + bbase + (size_t)(j0 + jr) * D3_ + 512 + hoff;
#pragma unroll
    for (int cc = 0; cc < 4; cc++){
      const int c = cg + (cc << 2);
      const float4 kv4 = *reinterpret_cast<const float4*>(krow + (c << 2));
      *reinterpret_cast<float4*>(&Ks[(jr << 6) + ((c ^ (jr & 7)) << 2)]) = kv4;
      const float4 vv4 = *reinterpret_cast<const float4*>(krow + 512 + (c << 2));
      const int d0 = c << 2, jh = jr >> 2, jl = jr & 3;
      Vt[((d0 + 0) << 6) + ((jh ^ ((d0 + 0) & 7)) << 2) + jl] = vv4.x;
      Vt[((d0 + 1) << 6) + ((jh ^ ((d0 + 1) & 7)) << 2) + jl] = vv4.y;
      Vt[((d0 + 2) << 6) + ((jh ^ ((d0 + 2) & 7)) << 2) + jl] = vv4.z;
      Vt[((d0 + 3) << 6) + ((jh ^ ((d0 + 3) & 7)) << 2) + jl] = vv4.w;
    }
    __syncthreads();
    float s0p0 = 0.f, s0p1 = 0.f, s0p2 = 0.f, s0p3 = 0.f;
    float s1p0 = 0.f, s1p1 = 0.f, s1p2 = 0.f, s1p3 = 0.f;
#pragma unroll
    for (int c = 0; c < 16; c++){
      const float4 kx = *reinterpret_cast<const float4*>(
          &Ks[(lane << 6) + ((c ^ (lane & 7)) << 2)]);
      const float4 q0c = *reinterpret_cast<const float4*>(&qs[w << 1][c << 2]);
      const float4 q1c = *reinterpret_cast<const float4*>(&qs[(w << 1) + 1][c << 2]);
      s0p0 = fmaf(q0c.x, kx.x, s0p0); s0p1 = fmaf(q0c.y, kx.y, s0p1);
      s0p2 = fmaf(q0c.z, kx.z, s0p2); s0p3 = fmaf(q0c.w, kx.w, s0p3);
      s1p0 = fmaf(q1c.x, kx.x, s1p0); s1p1 = fmaf(q1c.y, kx.y, s1p1);
      s1p2 = fmaf(q1c.z, kx.z, s1p2); s1p3 = fmaf(q1c.w, kx.w, s1p3);
    }
    const float s0 = (s0p0 + s0p1) + (s0p2 + s0p3);
    const float s1 = (s1p0 + s1p1) + (s1p2 + s1p3);
    const int jg = j0 + lane;
    const float s0m = (jg <= qr0) ? s0 : -1e30f;
    const float s1m = (jg <= qr1) ? s1 : -1e30f;
    const float mn0 = fmaxf(m0, wredmax(s0m));
    const float mn1 = fmaxf(m1, wredmax(s1m));
    const float p0 = __expf(s0m - mn0);
    const float p1 = __expf(s1m - mn1);
    const float cr0 = __expf(m0 - mn0);
    const float cr1 = __expf(m1 - mn1);
    l0 = l0 * cr0 + p0;
    l1 = l1 * cr1 + p1;
    a0p0 *= cr0; a0p1 *= cr0; a0p2 *= cr0; a0p3 *= cr0;
    a1p0 *= cr1; a1p1 *= cr1; a1p2 *= cr1; a1p3 *= cr1;
    m0 = mn0; m1 = mn1;
    ps[w][0][lane] = p0;
    ps[w][1][lane] = p1;
#pragma unroll
    for (int c = 0; c < 16; c++){
      const float4 vx = *reinterpret_cast<const float4*>(
          &Vt[(lane << 6) + ((c ^ (lane & 7)) << 2)]);
      const float4 p0v = *reinterpret_cast<const float4*>(&ps[w][0][c << 2]);
      const float4 p1v = *reinterpret_cast<const float4*>(&ps[w][1][c << 2]);
      a0p0 = fmaf(p0v.x, vx.x, a0p0); a0p1 = fmaf(p0v.y, vx.y, a0p1);
      a0p2 = fmaf(p0v.z, vx.z, a0p2); a0p3 = fmaf(p0v.w, vx.w, a0p3);
      a1p0 = fmaf(p1v.x, vx.x, a1p0); a1p1 = fmaf(p1v.y, vx.y, a1p1);
      a1p2 = fmaf(p1v.z, vx.z, a1p2); a1p3 = fmaf(p1v.w, vx.w, a1p3);
    }
  }
  const float l0t = wred(l0);
  const float l1t = wred(l1);
  const int t0 = (b << 10) + qr0;
  o[(size_t)t0 * D_ + hoff + lane]       = ((a0p0 + a0p1) + (a0p2 + a0p3)) / l0t;
  o[(size_t)(t0 + 1) * D_ + hoff + lane] = ((a1p0 + a1p1) + (a1p2 + a1p3)) / l1t;
}

// ======================= host launcher =======================
extern "C" void kernel_launch(void* const* d_in, const int* in_sizes, int n_in,
                              void* d_out, int out_size, void* d_ws, size_t ws_size,
                              hipStream_t stream){
  const int*   ids  = (const int*)  d_in[0];
  const float* tok  = (const float*)d_in[1];
  const float* pos  = (const float*)d_in[2];
  const float* Wqkv = (const float*)d_in[3];
  const float* bqkv = (const float*)d_in[4];
  const float* Wo   = (const float*)d_in[5];
  const float* bo   = (const float*)d_in[6];
  const float* rW   = (const float*)d_in[7];
  const float* rb   = (const float*)d_in[8];
  const float* eW1  = (const float*)d_in[9];
  const float* eb1  = (const float*)d_in[10];
  const float* eW2  = (const float*)d_in[11];
  const float* eb2  = (const float*)d_in[12];
  const float* n1w  = (const float*)d_in[13];
  const float* n2w  = (const float*)d_in[14];
  const float* noww = (const float*)d_in[15];
  const float* lmW  = (const float*)d_in[16];

  float* out    = (float*)d_out;
  float* logits = out;                             // [T,V]
  float* aux    = out + (size_t)T_ * V_;           // [1]
  float* rlog   = aux + 1;                         // [L,T,E]

  float* ws = (float*)d_ws;
  size_t off = 0;
  float* x     = ws + off; off += (size_t)T_ * D_;
  float* h     = ws + off; off += (size_t)T_ * D_;
  float* qkv   = ws + off; off += (size_t)T_ * D3_;
  float* attno = ws + off; off += (size_t)T_ * D_;
  float* hid   = ws + off; off += (size_t)T_ * FF_;
  float* topw  = ws + off; off += T_;
  int* topi    = (int*)(ws + off); off += T_;
  int* perm    = (int*)(ws + off); off += T_;
  int* seg     = (int*)(ws + off); off += (E_ + 1);

  hipMemsetAsync(aux, 0, sizeof(float), stream);
  k_embed<<<T_, 256, 0, stream>>>(ids, tok, pos, x);

  for (int l = 0; l < L_; l++){
    // --- attention block ---
    k_rmsnorm<<<T_, 256, 0, stream>>>(x, n1w + (size_t)l * D_, h);
    k_mgemm<64, 128, 3, 0, false, false, 0><<<dim3(D3_ / 128, T_ / 64), 256, 0, stream>>>(
        h, Wqkv + (size_t)l * D_ * D3_, bqkv + (size_t)l * D3_, qkv,
        T_, D3_, D_, seg, perm, topw);
    k_attn3<<<B_ * H_ * (S_ / 8), 256, 0, stream>>>(qkv, attno);
    k_mgemm<64, 64, 3, 1, false, false, 0><<<dim3(D_ / 64, T_ / 64), 256, 0, stream>>>(
        attno, Wo + (size_t)l * D_ * D_, bo + (size_t)l * D_, x,
        T_, D_, D_, seg, perm, topw);
    // --- MoE block (fused norm+router, parallel scan) ---
    k_norm_router<<<T_, 64, 0, stream>>>(x, n2w + (size_t)l * D_,
        rW + (size_t)l * D_ * E_, rb + (size_t)l * E_,
        h, rlog + (size_t)l * T_ * E_, topw, topi);
    k_route_scan2<<<1, 1024, 0, stream>>>(topi, rlog + (size_t)l * T_ * E_, seg, perm, aux);
    k_mgemm<64, 128, 3, 2, true, true, 0><<<dim3(FF_ / 128, T_ / 64, E_), 256, 0, stream>>>(
        h, eW1 + (size_t)l * E_ * D_ * FF_, eb1 + (size_t)l * E_ * FF_, hid,
        T_, FF_, D_, seg, perm, topw);
    k_mgemm<64, 64, 3, 3, true, false, 0><<<dim3(D_ / 64, T_ / 64, E_), 256, 0, stream>>>(
        hid, eW2 + (size_t)l * E_ * FF_ * D_, eb2 + (size_t)l * E_ * D_, x,
        T_, D_, FF_, seg, perm, topw);
  }

  // --- final norm + LM head (f16-hi, XCD-chunked 1D grid: 16 rowTiles) ---
  k_rmsnorm<<<T_, 256, 0, stream>>>(x, noww, h);
  k_mgemm<128, 128, 1, 4, false, false, 16><<<(T_ / 128) * (V_ / 128), 256, 0, stream>>>(
      h, lmW, noww /*unused*/, logits, T_, V_, D_, seg, perm, topw);
}

// Round 7
// 3151.844 us; speedup vs baseline: 6.2643x; 1.4759x over previous
//
#include <hip/hip_runtime.h>

// ==== model dims (fixed by the reference) ====
constexpr int B_  = 2, S_ = 1024, T_ = 2048;   // T = B*S tokens
constexpr int D_  = 512, H_ = 8, DH_ = 64;
constexpr int L_  = 12, E_ = 8, FF_ = 2048;
constexpr int V_  = 32000, D3_ = 1536;

using half8_t = __attribute__((ext_vector_type(8))) _Float16;
using half2_t = __attribute__((ext_vector_type(2))) _Float16;
using f32x4_t = __attribute__((ext_vector_type(4))) float;

// ---------- helpers ----------
__device__ __forceinline__ float wred(float v){
#pragma unroll
  for (int off = 32; off; off >>= 1) v += __shfl_xor(v, off);
  return v;
}
__device__ __forceinline__ float gelu_f(float v){
  return 0.5f * v * (1.f + erff(v * 0.70710678118654752f));
}

// ---------- embedding ----------
__global__ void k_embed(const int* __restrict__ ids, const float* __restrict__ tok,
                        const float* __restrict__ pos, float* __restrict__ x){
  int t = blockIdx.x;
  int s = t & (S_ - 1);
  int id = ids[t];
  const float* tr = tok + (size_t)id * D_;
  const float* pr = pos + (size_t)s  * D_;
  float* xr = x + (size_t)t * D_;
  for (int d = threadIdx.x; d < D_; d += blockDim.x) xr[d] = tr[d] + pr[d];
}

// ---------- rmsnorm (norm1 + final norm) ----------
__global__ __launch_bounds__(256) void k_rmsnorm(const float* __restrict__ x,
                                                 const float* __restrict__ w,
                                                 float* __restrict__ h){
  int t = blockIdx.x;
  const float* xr = x + (size_t)t * D_;
  float* hr = h + (size_t)t * D_;
  float ss = 0.f;
  for (int d = threadIdx.x; d < D_; d += 256){ float v = xr[d]; ss += v * v; }
  ss = wred(ss);
  __shared__ float sp[4];
  __shared__ float sscale;
  if ((threadIdx.x & 63) == 0) sp[threadIdx.x >> 6] = ss;
  __syncthreads();
  if (threadIdx.x == 0){
    float tot = sp[0] + sp[1] + sp[2] + sp[3];
    sscale = rsqrtf(tot / (float)D_ + 1e-6f);
  }
  __syncthreads();
  float sc = sscale;
  for (int d = threadIdx.x; d < D_; d += 256) hr[d] = xr[d] * sc * w[d];
}

// ---------- fused rmsnorm#2 + router: one wave per token ----------
__global__ __launch_bounds__(64) void k_norm_router(
    const float* __restrict__ x, const float* __restrict__ nw,
    const float* __restrict__ rW, const float* __restrict__ rb,
    float* __restrict__ h, float* __restrict__ rl_out,
    float* __restrict__ topw, int* __restrict__ topi){
  const int t = blockIdx.x, lane = threadIdx.x;
  const float* xr = x + (size_t)t * D_;
  const float4 xv0 = *reinterpret_cast<const float4*>(xr + (lane << 2));
  const float4 xv1 = *reinterpret_cast<const float4*>(xr + 256 + (lane << 2));
  float ss = xv0.x*xv0.x + xv0.y*xv0.y + xv0.z*xv0.z + xv0.w*xv0.w
           + xv1.x*xv1.x + xv1.y*xv1.y + xv1.z*xv1.z + xv1.w*xv1.w;
  ss = wred(ss);
  const float sc = rsqrtf(ss * (1.f / (float)D_) + 1e-6f);
  const float4 w0 = *reinterpret_cast<const float4*>(nw + (lane << 2));
  const float4 w1 = *reinterpret_cast<const float4*>(nw + 256 + (lane << 2));
  float hv[8];
  hv[0] = xv0.x*sc*w0.x; hv[1] = xv0.y*sc*w0.y; hv[2] = xv0.z*sc*w0.z; hv[3] = xv0.w*sc*w0.w;
  hv[4] = xv1.x*sc*w1.x; hv[5] = xv1.y*sc*w1.y; hv[6] = xv1.z*sc*w1.z; hv[7] = xv1.w*sc*w1.w;
  float* hr = h + (size_t)t * D_;
  *reinterpret_cast<float4*>(hr + (lane << 2))       = make_float4(hv[0], hv[1], hv[2], hv[3]);
  *reinterpret_cast<float4*>(hr + 256 + (lane << 2)) = make_float4(hv[4], hv[5], hv[6], hv[7]);
  float acc[8] = {0,0,0,0,0,0,0,0};
#pragma unroll
  for (int u = 0; u < 8; u++){
    const int d = (u < 4) ? ((lane << 2) + u) : (256 + (lane << 2) + u - 4);
    const float4 ra = *reinterpret_cast<const float4*>(rW + (size_t)d * E_);
    const float4 rb4 = *reinterpret_cast<const float4*>(rW + (size_t)d * E_ + 4);
    acc[0] += hv[u]*ra.x;  acc[1] += hv[u]*ra.y;  acc[2] += hv[u]*ra.z;  acc[3] += hv[u]*ra.w;
    acc[4] += hv[u]*rb4.x; acc[5] += hv[u]*rb4.y; acc[6] += hv[u]*rb4.z; acc[7] += hv[u]*rb4.w;
  }
  float rl[8];
#pragma unroll
  for (int e = 0; e < 8; e++) rl[e] = wred(acc[e]) + rb[e];
  float mx = rl[0];
#pragma unroll
  for (int e = 1; e < 8; e++) mx = fmaxf(mx, rl[e]);
  float p[8], s = 0.f;
#pragma unroll
  for (int e = 0; e < 8; e++){ p[e] = __expf(rl[e] - mx); s += p[e]; }
  const float inv = 1.f / s;
  int arg = 0; float best = rl[0];
#pragma unroll
  for (int e = 1; e < 8; e++) if (rl[e] > best){ best = rl[e]; arg = e; }
  if (lane == 0){
#pragma unroll
    for (int e = 0; e < 8; e++) rl_out[(size_t)t * E_ + e] = rl[e];
    topw[t] = p[arg] * inv;
    topi[t] = arg;
  }
}

// ---------- parallel routing scan: one 1024-thread block ----------
__global__ __launch_bounds__(1024) void k_route_scan2(
    const int* __restrict__ topi, const float* __restrict__ rl,
    int* __restrict__ seg, int* __restrict__ perm, float* __restrict__ aux){
  __shared__ int cnt[8], segs[9], cur[8];
  __shared__ float psums[8];
  const int tid = threadIdx.x;
  if (tid < 8){ cnt[tid] = 0; psums[tid] = 0.f; }
  __syncthreads();
  const int t0 = tid, t1 = tid + 1024;
  const int e0 = topi[t0], e1 = topi[t1];
  atomicAdd(&cnt[e0], 1);
  atomicAdd(&cnt[e1], 1);
  float ps[8] = {0,0,0,0,0,0,0,0};
#pragma unroll
  for (int k = 0; k < 2; k++){
    const float* r = rl + (size_t)(k ? t1 : t0) * E_;
    float v[8];
#pragma unroll
    for (int e = 0; e < 8; e++) v[e] = r[e];
    float mx = v[0];
#pragma unroll
    for (int e = 1; e < 8; e++) mx = fmaxf(mx, v[e]);
    float s = 0.f;
#pragma unroll
    for (int e = 0; e < 8; e++){ v[e] = __expf(v[e] - mx); s += v[e]; }
    const float is = 1.f / s;
#pragma unroll
    for (int e = 0; e < 8; e++) ps[e] += v[e] * is;
  }
#pragma unroll
  for (int e = 0; e < 8; e++) ps[e] = wred(ps[e]);
  if ((tid & 63) == 0){
#pragma unroll
    for (int e = 0; e < 8; e++) atomicAdd(&psums[e], ps[e]);
  }
  __syncthreads();
  if (tid == 0){
    segs[0] = 0;
#pragma unroll
    for (int e = 0; e < 8; e++) segs[e + 1] = segs[e] + cnt[e];
#pragma unroll
    for (int e = 0; e < 8; e++) cur[e] = segs[e];
  }
  __syncthreads();
  if (tid < 9) seg[tid] = segs[tid];
  const int p0 = atomicAdd(&cur[e0], 1); perm[p0] = t0;
  const int p1 = atomicAdd(&cur[e1], 1); perm[p1] = t1;
  if (tid == 0){
    float av = 0.f;
#pragma unroll
    for (int e = 0; e < 8; e++) av += (float)cnt[e] * psums[e];
    aux[0] += 8.f * av * (1.f / ((float)T_ * (float)T_));
  }
}

// ======================================================================
// MFMA GEMM, fp16x2 split (NPROD=3, fp32-grade) or single f16-hi (NPROD=1).
// LDS layout = fragment-native: [sub16][64 lanes][8 f16], lidx ^= (sub&7).
// EPI: 0=bias+store 1=bias+acc 2=bias+gelu+store(MoE hid) 3=moe scaled acc 4=store
// SWZROWS>0: 1D grid, XCD-chunked swizzle, rowTile = lb % SWZROWS.
// ======================================================================
template<int BM, int BN, int NPROD, int EPI, bool MOE, bool APERM, int SWZROWS>
__global__ __launch_bounds__(256) void k_mgemm(
    const float* __restrict__ A, const float* __restrict__ Bm,
    const float* __restrict__ bias, float* __restrict__ C,
    int M, int N, int K,
    const int* __restrict__ seg, const int* __restrict__ perm,
    const float* __restrict__ topw){
  constexpr int FM = BM / 32, FN = BN / 32;
  const int tid = threadIdx.x;
  int rowTile, colTile;
  if (SWZROWS > 0){
    const int nwg = gridDim.x;
    const int bid = blockIdx.x;
    const int lb = (bid & 7) * (nwg >> 3) + (bid >> 3);   // XCD-chunked (nwg%8==0)
    rowTile = lb % SWZROWS;
    colTile = lb / SWZROWS;
  } else {
    colTile = blockIdx.x; rowTile = blockIdx.y;
  }
  int e = 0, s0 = 0, cnt = M;
  if (MOE){ e = blockIdx.z; s0 = seg[e]; cnt = seg[e + 1] - s0; }
  const int row0 = rowTile * BM, col0 = colTile * BN;
  if (MOE && row0 >= cnt) return;
  const float* Bp = Bm + (size_t)e * K * N;
  const float* bp = bias + (size_t)e * N;

  __shared__ __align__(16) _Float16 Ah[BM * 32];
  __shared__ __align__(16) _Float16 Al[NPROD == 3 ? BM * 32 : 8];
  __shared__ __align__(16) _Float16 Bh[BN * 32];
  __shared__ __align__(16) _Float16 Bl[NPROD == 3 ? BN * 32 : 8];

  // A loader
  const int am = (BM == 64) ? (tid >> 2) : (tid >> 1);
  const int agrow = row0 + am;
  const bool aval = agrow < cnt;
  const float* Arow = nullptr;
  if (aval){
    int ridx = APERM ? perm[s0 + agrow] : (MOE ? s0 + agrow : agrow);
    Arow = A + (size_t)ridx * K;
  }
  const int asub = am >> 4;
  // B loader
  const int cb = (BN == 128) ? ((tid & 31) << 2) : ((tid & 15) << 2);
  const int p0 = (BN == 128) ? (tid >> 5) : (tid >> 4);
  constexpr int NBI = (BN == 128) ? 2 : 1;

  const int lane = tid & 63, w = tid >> 6;
  const int wm0 = (w >> 1) * (BM / 2), wn0 = (w & 1) * (BN / 2);

  f32x4_t acc_hh[FM][FN];
  f32x4_t acc_mx[NPROD == 3 ? FM : 1][NPROD == 3 ? FN : 1];
#pragma unroll
  for (int i = 0; i < FM; i++)
#pragma unroll
    for (int j = 0; j < FN; j++){
      acc_hh[i][j] = (f32x4_t){0.f, 0.f, 0.f, 0.f};
      if (NPROD == 3) acc_mx[i][j] = (f32x4_t){0.f, 0.f, 0.f, 0.f};
    }

  for (int k0 = 0; k0 < K; k0 += 32){
    // ---- stage A ----
    if (BM == 64){
      const int kg = tid & 3;
      float4 av0 = make_float4(0,0,0,0), av1 = make_float4(0,0,0,0);
      if (aval){
        av0 = *reinterpret_cast<const float4*>(Arow + k0 + (kg << 3));
        av1 = *reinterpret_cast<const float4*>(Arow + k0 + (kg << 3) + 4);
      }
      const float a8[8] = {av0.x, av0.y, av0.z, av0.w, av1.x, av1.y, av1.z, av1.w};
      half8_t hi, lo;
#pragma unroll
      for (int u = 0; u < 8; u++){
        hi[u] = (_Float16)a8[u];
        if (NPROD == 3) lo[u] = (_Float16)((a8[u] - (float)hi[u]) * 2048.f);
      }
      const int lidx = (am & 15) + (kg << 4);
      const int base = asub * 512 + ((lidx ^ (asub & 7)) << 3);
      *reinterpret_cast<half8_t*>(&Ah[base]) = hi;
      if (NPROD == 3) *reinterpret_cast<half8_t*>(&Al[base]) = lo;
    } else {
      const int kgb = (tid & 1) << 1;
#pragma unroll
      for (int kq = 0; kq < 2; kq++){
        const int kg = kgb + kq;
        float4 av0 = make_float4(0,0,0,0), av1 = make_float4(0,0,0,0);
        if (aval){
          av0 = *reinterpret_cast<const float4*>(Arow + k0 + (kg << 3));
          av1 = *reinterpret_cast<const float4*>(Arow + k0 + (kg << 3) + 4);
        }
        const float a8[8] = {av0.x, av0.y, av0.z, av0.w, av1.x, av1.y, av1.z, av1.w};
        half8_t hi;
#pragma unroll
        for (int u = 0; u < 8; u++) hi[u] = (_Float16)a8[u];
        const int lidx = (am & 15) + (kg << 4);
        *reinterpret_cast<half8_t*>(&Ah[asub * 512 + ((lidx ^ (asub & 7)) << 3)]) = hi;
      }
    }
    // ---- stage B ----
#pragma unroll
    for (int it = 0; it < NBI; it++){
      const int kk = ((BN == 128) ? (p0 + (it << 3)) : p0) << 1;
      const int kg = kk >> 3, e2 = kk & 7;
      const float4 b0 = *reinterpret_cast<const float4*>(Bp + (size_t)(k0 + kk) * N + col0 + cb);
      const float4 b1 = *reinterpret_cast<const float4*>(Bp + (size_t)(k0 + kk + 1) * N + col0 + cb);
      const float b0a[4] = {b0.x, b0.y, b0.z, b0.w};
      const float b1a[4] = {b1.x, b1.y, b1.z, b1.w};
#pragma unroll
      for (int j = 0; j < 4; j++){
        const int c = cb + j, sub = c >> 4;
        const int lidx = (c & 15) + (kg << 4);
        const int base = sub * 512 + ((lidx ^ (sub & 7)) << 3) + e2;
        _Float16 h0 = (_Float16)b0a[j], h1 = (_Float16)b1a[j];
        *reinterpret_cast<half2_t*>(&Bh[base]) = (half2_t){h0, h1};
        if (NPROD == 3){
          _Float16 l0 = (_Float16)((b0a[j] - (float)h0) * 2048.f);
          _Float16 l1 = (_Float16)((b1a[j] - (float)h1) * 2048.f);
          *reinterpret_cast<half2_t*>(&Bl[base]) = (half2_t){l0, l1};
        }
      }
    }
    __syncthreads();
    // ---- fragments + MFMA ----
    half8_t fAh[FM], fBh[FN];
    half8_t fAl[NPROD == 3 ? FM : 1], fBl[NPROD == 3 ? FN : 1];
#pragma unroll
    for (int fm = 0; fm < FM; fm++){
      const int s = (wm0 >> 4) + fm;
      const int ofs = s * 512 + ((lane ^ (s & 7)) << 3);
      fAh[fm] = *reinterpret_cast<const half8_t*>(&Ah[ofs]);
      if (NPROD == 3) fAl[fm] = *reinterpret_cast<const half8_t*>(&Al[ofs]);
    }
#pragma unroll
    for (int fn = 0; fn < FN; fn++){
      const int s = (wn0 >> 4) + fn;
      const int ofs = s * 512 + ((lane ^ (s & 7)) << 3);
      fBh[fn] = *reinterpret_cast<const half8_t*>(&Bh[ofs]);
      if (NPROD == 3) fBl[fn] = *reinterpret_cast<const half8_t*>(&Bl[ofs]);
    }
#pragma unroll
    for (int fm = 0; fm < FM; fm++)
#pragma unroll
      for (int fn = 0; fn < FN; fn++){
        acc_hh[fm][fn] = __builtin_amdgcn_mfma_f32_16x16x32_f16(
            fAh[fm], fBh[fn], acc_hh[fm][fn], 0, 0, 0);
        if (NPROD == 3){
          acc_mx[fm][fn] = __builtin_amdgcn_mfma_f32_16x16x32_f16(
              fAh[fm], fBl[fn], acc_mx[fm][fn], 0, 0, 0);
          acc_mx[fm][fn] = __builtin_amdgcn_mfma_f32_16x16x32_f16(
              fAl[fm], fBh[fn], acc_mx[fm][fn], 0, 0, 0);
        }
      }
    __syncthreads();
  }

  // ---- epilogue ----
  const int lr = lane & 15, kg4 = lane >> 4;
#pragma unroll
  for (int fm = 0; fm < FM; fm++){
#pragma unroll
    for (int reg = 0; reg < 4; reg++){
      const int grow = row0 + wm0 + fm * 16 + (kg4 << 2) + reg;
      if (grow >= cnt) continue;
      int trow = 0; float tw = 0.f;
      if (EPI == 3){ trow = perm[s0 + grow]; tw = topw[trow]; }
#pragma unroll
      for (int fn = 0; fn < FN; fn++){
        const int col = col0 + wn0 + fn * 16 + lr;
        float v = acc_hh[fm][fn][reg];
        if (NPROD == 3) v += acc_mx[fm][fn][reg] * (1.f / 2048.f);
        if (EPI == 0){
          C[(size_t)grow * N + col] = v + bp[col];
        } else if (EPI == 1){
          C[(size_t)grow * N + col] += v + bp[col];
        } else if (EPI == 2){
          C[(size_t)(s0 + grow) * N + col] = gelu_f(v + bp[col]);
        } else if (EPI == 3){
          C[(size_t)trow * N + col] += tw * (v + bp[col]);
        } else {
          C[(size_t)grow * N + col] = v;
        }
      }
    }
  }
}

// ======================================================================
// causal attention v4: MFMA flash, f16x2-split (fp32-grade).
// Block = 256 thr / 4 waves = one (b, h, 64-query tile); grid = 256.
// Swapped QK^T: D[key][q] = mfma(A=K, B=Q)  -> softmax reduce = 16 regs + 2 shfl.
// PV: O^T[d][q] = mfma(A=V^T, B=P); P transposed via per-wave private LDS.
// Fragment mapping (HW-verified by k_mgemm): A[row=lane&15][k=(lane>>4)*8+e],
// B[k=(lane>>4)*8+e][col=lane&15], D[row=(lane>>4)*4+reg][col=lane&15].
// ======================================================================
__global__ __launch_bounds__(256) void k_attn4(const float* __restrict__ qkv,
                                               float* __restrict__ o){
  // K: B-operand layout [kstep_d=2][sub_key=4][lidx=(key&15)+kgd*16][e=d&7]
  // V: A-operand layout [kstep_key=2][sub_d=4][swz(lidx=(d&15)+kgk*16)][e=key&7]
  __shared__ __align__(16) _Float16 Khi[4096], Klo[4096], Vhi[4096], Vlo[4096];
  __shared__ __align__(16) float pbuf[4][16 * 68];
  const int tid = threadIdx.x, w = tid >> 6, lane = tid & 63;
  const int lr = lane & 15, g = lane >> 4;
  const int bid = blockIdx.x;
  const int qt = bid & 15, h = (bid >> 4) & 7, b = bid >> 7;
  const size_t bbase = (size_t)(b << 10) * D3_;
  const int hoff = h * 64;
  const int qg = (qt << 6) + (w << 4) + lr;      // this lane's query (col index)

  // ---- Q fragments (B-operand), scale 1/8 folded (exact pow2) ----
  half8_t qhi[2], qlo[2];
#pragma unroll
  for (int ks = 0; ks < 2; ks++){
    const float* qp = qkv + bbase + (size_t)qg * D3_ + hoff + ks * 32 + g * 8;
    const float4 f0 = *reinterpret_cast<const float4*>(qp);
    const float4 f1 = *reinterpret_cast<const float4*>(qp + 4);
    const float qa[8] = {f0.x, f0.y, f0.z, f0.w, f1.x, f1.y, f1.z, f1.w};
#pragma unroll
    for (int e = 0; e < 8; e++){
      const float v = qa[e] * 0.125f;
      const _Float16 hi = (_Float16)v;
      qhi[ks][e] = hi;
      qlo[ks][e] = (_Float16)((v - (float)hi) * 2048.f);
    }
  }

  float m = -1e30f, l = 0.f;
  f32x4_t oacc[4];
#pragma unroll
  for (int s = 0; s < 4; s++) oacc[s] = (f32x4_t){0.f, 0.f, 0.f, 0.f};

  // staging thread roles
  const int kK = tid >> 2, quad = tid & 3;        // K: key row, d-quarter
  const int kp = tid >> 3, oct = tid & 7;         // V: key pair, d-octet
  const int ntiles = qt + 1;

  for (int kt = 0; kt < ntiles; kt++){
    const int j0 = kt << 6;
    __syncthreads();                               // prior-tile reads done
    // ---- stage K (hi/lo, fragment-native; coalesced 64B/lane) ----
    {
      const float* kr = qkv + bbase + (size_t)(j0 + kK) * D3_ + 512 + hoff + quad * 16;
      const float4 f0 = *reinterpret_cast<const float4*>(kr);
      const float4 f1 = *reinterpret_cast<const float4*>(kr + 4);
      const float4 f2 = *reinterpret_cast<const float4*>(kr + 8);
      const float4 f3 = *reinterpret_cast<const float4*>(kr + 12);
      const float ka[16] = {f0.x,f0.y,f0.z,f0.w, f1.x,f1.y,f1.z,f1.w,
                            f2.x,f2.y,f2.z,f2.w, f3.x,f3.y,f3.z,f3.w};
      const int ksd = quad >> 1;
#pragma unroll
      for (int ch = 0; ch < 2; ch++){
        const int kgd = ((quad << 1) + ch) & 3;
        const int base = ksd * 2048 + (kK >> 4) * 512 + (((kK & 15) + (kgd << 4)) << 3);
        half8_t hi, lo;
#pragma unroll
        for (int e = 0; e < 8; e++){
          const float v = ka[ch * 8 + e];
          const _Float16 hv = (_Float16)v;
          hi[e] = hv;
          lo[e] = (_Float16)((v - (float)hv) * 2048.f);
        }
        *reinterpret_cast<half8_t*>(&Khi[base]) = hi;
        *reinterpret_cast<half8_t*>(&Klo[base]) = lo;
      }
    }
    // ---- stage V^T (hi/lo, fragment-native + XOR swizzle; half2 per d) ----
    {
      const int k0 = kp << 1;
      const float* vr = qkv + bbase + (size_t)(j0 + k0) * D3_ + 1024 + hoff + oct * 8;
      const float4 a0 = *reinterpret_cast<const float4*>(vr);
      const float4 a1 = *reinterpret_cast<const float4*>(vr + 4);
      const float4 b0 = *reinterpret_cast<const float4*>(vr + D3_);
      const float4 b1 = *reinterpret_cast<const float4*>(vr + D3_ + 4);
      const float va[8] = {a0.x,a0.y,a0.z,a0.w, a1.x,a1.y,a1.z,a1.w};
      const float vb[8] = {b0.x,b0.y,b0.z,b0.w, b1.x,b1.y,b1.z,b1.w};
      const int ksk = kp >> 4, kgk = (kp >> 2) & 3, e0 = (kp & 3) << 1;
#pragma unroll
      for (int j = 0; j < 8; j++){
        const int d = oct * 8 + j;
        const int lidx = (d & 15) + (kgk << 4);
        const int sw = lidx ^ kgk ^ (ksk << 2);
        const int fa = ksk * 2048 + (d >> 4) * 512 + (sw << 3) + e0;
        const _Float16 h0 = (_Float16)va[j], h1 = (_Float16)vb[j];
        *reinterpret_cast<half2_t*>(&Vhi[fa]) = (half2_t){h0, h1};
        const _Float16 l0 = (_Float16)((va[j] - (float)h0) * 2048.f);
        const _Float16 l1 = (_Float16)((vb[j] - (float)h1) * 2048.f);
        *reinterpret_cast<half2_t*>(&Vlo[fa]) = (half2_t){l0, l1};
      }
    }
    __syncthreads();

    // ---- QK^T: D[key][q], 3-product split ----
    f32x4_t dfr[4];
#pragma unroll
    for (int s = 0; s < 4; s++){
      f32x4_t acc = (f32x4_t){0.f, 0.f, 0.f, 0.f};
      f32x4_t mix = (f32x4_t){0.f, 0.f, 0.f, 0.f};
#pragma unroll
      for (int ks = 0; ks < 2; ks++){
        const int base = ks * 2048 + s * 512 + lane * 8;
        const half8_t khi = *reinterpret_cast<const half8_t*>(&Khi[base]);
        const half8_t klo = *reinterpret_cast<const half8_t*>(&Klo[base]);
        acc = __builtin_amdgcn_mfma_f32_16x16x32_f16(khi, qhi[ks], acc, 0, 0, 0);
        mix = __builtin_amdgcn_mfma_f32_16x16x32_f16(khi, qlo[ks], mix, 0, 0, 0);
        mix = __builtin_amdgcn_mfma_f32_16x16x32_f16(klo, qhi[ks], mix, 0, 0, 0);
      }
#pragma unroll
      for (int r = 0; r < 4; r++) dfr[s][r] = acc[r] + mix[r] * (1.f / 2048.f);
    }
    // ---- causal mask (diagonal tile only) ----
    if (kt == qt){
#pragma unroll
      for (int s = 0; s < 4; s++)
#pragma unroll
        for (int r = 0; r < 4; r++){
          const int keyg = j0 + (g << 2) + r + (s << 4);
          if (keyg > qg) dfr[s][r] = -1e30f;
        }
    }
    // ---- online softmax (per q = lr; reduce over 16 regs + shfl 16,32) ----
    float mloc = dfr[0][0];
#pragma unroll
    for (int s = 0; s < 4; s++)
#pragma unroll
      for (int r = 0; r < 4; r++) mloc = fmaxf(mloc, dfr[s][r]);
    mloc = fmaxf(mloc, __shfl_xor(mloc, 16));
    mloc = fmaxf(mloc, __shfl_xor(mloc, 32));
    const float mn = fmaxf(m, mloc);
    const float cr = __expf(m - mn);
    float psum = 0.f;
#pragma unroll
    for (int s = 0; s < 4; s++)
#pragma unroll
      for (int r = 0; r < 4; r++){
        const float p = __expf(dfr[s][r] - mn);
        psum += p;
        pbuf[w][lr * 68 + (s << 4) + (g << 2) + r] = p;   // [q][key]
      }
    psum += __shfl_xor(psum, 16);
    psum += __shfl_xor(psum, 32);
    l = l * cr + psum;
    m = mn;
#pragma unroll
    for (int s = 0; s < 4; s++)
#pragma unroll
      for (int r = 0; r < 4; r++) oacc[s][r] *= cr;

    // ---- P -> B-operand fragments (per-wave LDS readback, hi/lo split) ----
    half8_t phi[2], plo[2];
#pragma unroll
    for (int ks = 0; ks < 2; ks++){
      const float* pp = &pbuf[w][lr * 68 + ks * 32 + g * 8];
      const float4 p0 = *reinterpret_cast<const float4*>(pp);
      const float4 p1 = *reinterpret_cast<const float4*>(pp + 4);
      const float pa[8] = {p0.x,p0.y,p0.z,p0.w, p1.x,p1.y,p1.z,p1.w};
#pragma unroll
      for (int e = 0; e < 8; e++){
        const _Float16 hv = (_Float16)pa[e];
        phi[ks][e] = hv;
        plo[ks][e] = (_Float16)((pa[e] - (float)hv) * 2048.f);
      }
    }
    // ---- PV: O^T[d][q] += V^T x P, 3-product split ----
#pragma unroll
    for (int s = 0; s < 4; s++){
      f32x4_t mix = (f32x4_t){0.f, 0.f, 0.f, 0.f};
#pragma unroll
      for (int ks = 0; ks < 2; ks++){
        const int sw = lane ^ g ^ (ks << 2);
        const int base = ks * 2048 + s * 512 + sw * 8;
        const half8_t vhi = *reinterpret_cast<const half8_t*>(&Vhi[base]);
        const half8_t vlo = *reinterpret_cast<const half8_t*>(&Vlo[base]);
        oacc[s] = __builtin_amdgcn_mfma_f32_16x16x32_f16(vhi, phi[ks], oacc[s], 0, 0, 0);
        mix = __builtin_amdgcn_mfma_f32_16x16x32_f16(vhi, plo[ks], mix, 0, 0, 0);
        mix = __builtin_amdgcn_mfma_f32_16x16x32_f16(vlo, phi[ks], mix, 0, 0, 0);
      }
#pragma unroll
      for (int r = 0; r < 4; r++) oacc[s][r] += mix[r] * (1.f / 2048.f);
    }
  }

  // ---- epilogue: O[q][d] = oacc/l (lane: q=lr, d=g*4+r+s*16) ----
  const float linv = 1.f / l;
  float* orow = o + (size_t)((b << 10) + qg) * D_ + hoff;
#pragma unroll
  for (int s = 0; s < 4; s++)
#pragma unroll
    for (int r = 0; r < 4; r++){
      const int d = (g << 2) + r + (s << 4);
      orow[d] = oacc[s][r] * linv;
    }
}

// ======================= host launcher =======================
extern "C" void kernel_launch(void* const* d_in, const int* in_sizes, int n_in,
                              void* d_out, int out_size, void* d_ws, size_t ws_size,
                              hipStream_t stream){
  const int*   ids  = (const int*)  d_in[0];
  const float* tok  = (const float*)d_in[1];
  const float* pos  = (const float*)d_in[2];
  const float* Wqkv = (const float*)d_in[3];
  const float* bqkv = (const float*)d_in[4];
  const float* Wo   = (const float*)d_in[5];
  const float* bo   = (const float*)d_in[6];
  const float* rW   = (const float*)d_in[7];
  const float* rb   = (const float*)d_in[8];
  const float* eW1  = (const float*)d_in[9];
  const float* eb1  = (const float*)d_in[10];
  const float* eW2  = (const float*)d_in[11];
  const float* eb2  = (const float*)d_in[12];
  const float* n1w  = (const float*)d_in[13];
  const float* n2w  = (const float*)d_in[14];
  const float* noww = (const float*)d_in[15];
  const float* lmW  = (const float*)d_in[16];

  float* out    = (float*)d_out;
  float* logits = out;                             // [T,V]
  float* aux    = out + (size_t)T_ * V_;           // [1]
  float* rlog   = aux + 1;                         // [L,T,E]

  float* ws = (float*)d_ws;
  size_t off = 0;
  float* x     = ws + off; off += (size_t)T_ * D_;
  float* h     = ws + off; off += (size_t)T_ * D_;
  float* qkv   = ws + off; off += (size_t)T_ * D3_;
  float* attno = ws + off; off += (size_t)T_ * D_;
  float* hid   = ws + off; off += (size_t)T_ * FF_;
  float* topw  = ws + off; off += T_;
  int* topi    = (int*)(ws + off); off += T_;
  int* perm    = (int*)(ws + off); off += T_;
  int* seg     = (int*)(ws + off); off += (E_ + 1);

  hipMemsetAsync(aux, 0, sizeof(float), stream);
  k_embed<<<T_, 256, 0, stream>>>(ids, tok, pos, x);

  for (int l = 0; l < L_; l++){
    // --- attention block ---
    k_rmsnorm<<<T_, 256, 0, stream>>>(x, n1w + (size_t)l * D_, h);
    k_mgemm<64, 128, 3, 0, false, false, 0><<<dim3(D3_ / 128, T_ / 64), 256, 0, stream>>>(
        h, Wqkv + (size_t)l * D_ * D3_, bqkv + (size_t)l * D3_, qkv,
        T_, D3_, D_, seg, perm, topw);
    k_attn4<<<B_ * H_ * (S_ / 64), 256, 0, stream>>>(qkv, attno);
    k_mgemm<64, 64, 3, 1, false, false, 0><<<dim3(D_ / 64, T_ / 64), 256, 0, stream>>>(
        attno, Wo + (size_t)l * D_ * D_, bo + (size_t)l * D_, x,
        T_, D_, D_, seg, perm, topw);
    // --- MoE block (fused norm+router, parallel scan) ---
    k_norm_router<<<T_, 64, 0, stream>>>(x, n2w + (size_t)l * D_,
        rW + (size_t)l * D_ * E_, rb + (size_t)l * E_,
        h, rlog + (size_t)l * T_ * E_, topw, topi);
    k_route_scan2<<<1, 1024, 0, stream>>>(topi, rlog + (size_t)l * T_ * E_, seg, perm, aux);
    k_mgemm<64, 128, 3, 2, true, true, 0><<<dim3(FF_ / 128, T_ / 64, E_), 256, 0, stream>>>(
        h, eW1 + (size_t)l * E_ * D_ * FF_, eb1 + (size_t)l * E_ * FF_, hid,
        T_, FF_, D_, seg, perm, topw);
    k_mgemm<64, 64, 3, 3, true, false, 0><<<dim3(D_ / 64, T_ / 64, E_), 256, 0, stream>>>(
        hid, eW2 + (size_t)l * E_ * FF_ * D_, eb2 + (size_t)l * E_ * D_, x,
        T_, D_, FF_, seg, perm, topw);
  }

  // --- final norm + LM head (f16-hi, XCD-chunked 1D grid: 16 rowTiles) ---
  k_rmsnorm<<<T_, 256, 0, stream>>>(x, noww, h);
  k_mgemm<128, 128, 1, 4, false, false, 16><<<(T_ / 128) * (V_ / 128), 256, 0, stream>>>(
      h, lmW, noww /*unused*/, logits, T_, V_, D_, seg, perm, topw);
}